// Round 2
// baseline (672.851 us; speedup 1.0000x reference)
//
#include <hip/hip_runtime.h>
#include <stdint.h>

typedef unsigned int u32;
typedef unsigned char u8;

#define NIMG 64
#define W0   518
#define H0   518
#define HW   268324
#define HW4  67081
#define BPI  16

#define W1 259
#define N1 67081
#define W2 129
#define N2 16641
#define W3 64
#define N3 4096

// ---- workspace byte offsets ----
#define OFF_H1   0ULL            // u32[64][2][2048]
#define OFF_H2   1048576ULL      // u32[64][2][2048]
#define OFF_H3   2097152ULL      // u32[64][2][1024]
#define OFF_CNT  2621440ULL      // u32[64]
#define OFF_SELP 2621696ULL      // u32[128]
#define OFF_SELR 2622208ULL      // u32[128]
#define OFF_MED  2622720ULL      // float[128]
#define OFF_ABS  2623232ULL      // double[128]
#define OFF_RHO  2624256ULL      // double[64]
#define OFF_GACC 2624768ULL      // double[16]  (4 scales x {gx,cx,gy,cy})
#define OFF_SCI  2624896ULL      // float[128]
#define SMALL_END 2625408ULL
#define OFF_D    2625536ULL                    // float[64*268324]
#define OFF_P1   (OFF_D  + 68690944ULL)        // float[64*67081]
#define OFF_M1   (OFF_P1 + 17172736ULL)        // u8[64*67081]
#define OFF_P2   (OFF_M1 + 4293184ULL)         // float[64*16641]
#define OFF_M2   (OFF_P2 + 4260096ULL)         // u8[64*16641]
#define OFF_P3   (OFF_M2 + 1065024ULL)         // float[64*4096]
#define OFF_M3   (OFF_P3 + 1048576ULL)         // u8[64*4096]

__device__ __forceinline__ u32 f2key(float f) {
  u32 u = __float_as_uint(f);
  return (u & 0x80000000u) ? ~u : (u | 0x80000000u);
}
__device__ __forceinline__ float key2f(u32 k) {
  u32 u = (k & 0x80000000u) ? (k & 0x7fffffffu) : ~k;
  return __uint_as_float(u);
}

// ---------- pass 0: count + top-11-bit histogram ----------
__global__ __launch_bounds__(256) void k_hist0(const float4* __restrict__ p,
    const float4* __restrict__ y, const int4* __restrict__ m,
    u32* __restrict__ hist, u32* __restrict__ cnt)
{
  __shared__ u32 h[4096];
  __shared__ u32 blkcnt;
  for (int i = threadIdx.x; i < 4096; i += 256) h[i] = 0;
  if (threadIdx.x == 0) blkcnt = 0;
  __syncthreads();
  int img = blockIdx.x / BPI, blk = blockIdx.x % BPI;
  const float4* pb = p + (size_t)img * HW4;
  const float4* yb = y + (size_t)img * HW4;
  const int4* mb = m + (size_t)img * HW4;
  int lc = 0;
  for (int i = blk * 256 + threadIdx.x; i < HW4; i += BPI * 256) {
    float4 pv = pb[i], yv = yb[i];
    int4 mv = mb[i];
#define H0C(mm, pp, yy) if (mm) { lc++; atomicAdd(&h[f2key(pp) >> 21], 1u); atomicAdd(&h[2048u + (f2key(yy) >> 21)], 1u); }
    H0C(mv.x, pv.x, yv.x) H0C(mv.y, pv.y, yv.y) H0C(mv.z, pv.z, yv.z) H0C(mv.w, pv.w, yv.w)
#undef H0C
  }
  atomicAdd(&blkcnt, (u32)lc);
  __syncthreads();
  u32* gh = hist + (size_t)img * 4096;
  for (int b = threadIdx.x; b < 4096; b += 256) atomicAdd(&gh[b], h[b]);
  if (threadIdx.x == 0) atomicAdd(&cnt[img], blkcnt);
}

// ---------- pass 1: mid-11-bit histogram within selected top bin ----------
__global__ __launch_bounds__(256) void k_hist1(const float4* __restrict__ p,
    const float4* __restrict__ y, const int4* __restrict__ m,
    const u32* __restrict__ selp, u32* __restrict__ hist)
{
  __shared__ u32 h[4096];
  for (int i = threadIdx.x; i < 4096; i += 256) h[i] = 0;
  __syncthreads();
  int img = blockIdx.x / BPI, blk = blockIdx.x % BPI;
  u32 pp = selp[img * 2 + 0], py = selp[img * 2 + 1];
  const float4* pb = p + (size_t)img * HW4;
  const float4* yb = y + (size_t)img * HW4;
  const int4* mb = m + (size_t)img * HW4;
  for (int i = blk * 256 + threadIdx.x; i < HW4; i += BPI * 256) {
    float4 pv = pb[i], yv = yb[i];
    int4 mv = mb[i];
#define H1C(mm, pv_, yv_) if (mm) { \
      u32 kp = f2key(pv_); if ((kp >> 21) == pp) atomicAdd(&h[(kp >> 10) & 0x7FFu], 1u); \
      u32 ky = f2key(yv_); if ((ky >> 21) == py) atomicAdd(&h[2048u + ((ky >> 10) & 0x7FFu)], 1u); }
    H1C(mv.x, pv.x, yv.x) H1C(mv.y, pv.y, yv.y) H1C(mv.z, pv.z, yv.z) H1C(mv.w, pv.w, yv.w)
#undef H1C
  }
  __syncthreads();
  u32* gh = hist + (size_t)img * 4096;
  for (int b = threadIdx.x; b < 4096; b += 256) atomicAdd(&gh[b], h[b]);
}

// ---------- pass 2: low-10-bit histogram within selected 22-bit prefix ----------
__global__ __launch_bounds__(256) void k_hist2(const float4* __restrict__ p,
    const float4* __restrict__ y, const int4* __restrict__ m,
    const u32* __restrict__ selp, u32* __restrict__ hist)
{
  __shared__ u32 h[2048];
  for (int i = threadIdx.x; i < 2048; i += 256) h[i] = 0;
  __syncthreads();
  int img = blockIdx.x / BPI, blk = blockIdx.x % BPI;
  u32 pp = selp[img * 2 + 0], py = selp[img * 2 + 1];
  const float4* pb = p + (size_t)img * HW4;
  const float4* yb = y + (size_t)img * HW4;
  const int4* mb = m + (size_t)img * HW4;
  for (int i = blk * 256 + threadIdx.x; i < HW4; i += BPI * 256) {
    float4 pv = pb[i], yv = yb[i];
    int4 mv = mb[i];
#define H2C(mm, pv_, yv_) if (mm) { \
      u32 kp = f2key(pv_); if ((kp >> 10) == pp) atomicAdd(&h[kp & 0x3FFu], 1u); \
      u32 ky = f2key(yv_); if ((ky >> 10) == py) atomicAdd(&h[1024u + (ky & 0x3FFu)], 1u); }
    H2C(mv.x, pv.x, yv.x) H2C(mv.y, pv.y, yv.y) H2C(mv.z, pv.z, yv.z) H2C(mv.w, pv.w, yv.w)
#undef H2C
  }
  __syncthreads();
  u32* gh = hist + (size_t)img * 2048;
  for (int b = threadIdx.x; b < 2048; b += 256) atomicAdd(&gh[b], h[b]);
}

// ---------- select: one block per (img, arr); block-parallel scan ----------
__global__ __launch_bounds__(256) void k_sel(const u32* __restrict__ hist,
    const u32* __restrict__ cnt, u32* __restrict__ selp, u32* __restrict__ selr,
    float* __restrict__ med, int pass, int nbins)
{
  int t = blockIdx.x;                 // 0..127 = img*2 + arr
  int img = t >> 1;
  const u32* hh = hist + (size_t)t * nbins;
  u32 c = cnt[img];
  u32 target = (pass == 0) ? (c ? ((c - 1) >> 1) : 0u) : selr[t];
  int per = nbins >> 8;               // 8 or 4 bins per thread
  int b0 = threadIdx.x * per;
  u32 loc[8];
  u32 s = 0;
  for (int j = 0; j < per; j++) { loc[j] = hh[b0 + j]; s += loc[j]; }
  __shared__ u32 ps[256];
  ps[threadIdx.x] = s;
  __syncthreads();
  for (int off = 1; off < 256; off <<= 1) {
    u32 v = (threadIdx.x >= (u32)off) ? ps[threadIdx.x - off] : 0u;
    __syncthreads();
    ps[threadIdx.x] += v;
    __syncthreads();
  }
  u32 cum = ps[threadIdx.x] - s;      // exclusive prefix
  for (int j = 0; j < per; j++) {
    u32 v = loc[j];
    if (c && target >= cum && target < cum + v) {
      u32 bin = (u32)(b0 + j), rank = target - cum;
      if (pass == 0)      { selp[t] = bin; selr[t] = rank; }
      else if (pass == 1) { selp[t] = (selp[t] << 11) | bin; selr[t] = rank; }
      else                { u32 key = (selp[t] << 10) | bin; med[t] = key2f(key); }
    }
    cum += v;
  }
  if (pass == 2 && c == 0 && threadIdx.x == 0) med[t] = 0.0f;
}

// ---------- masked mean-abs-deviation from median ----------
__global__ __launch_bounds__(256) void k_absdev(const float4* __restrict__ p,
    const float4* __restrict__ y, const int4* __restrict__ m,
    const float* __restrict__ med, double* __restrict__ absdev)
{
  int img = blockIdx.x / BPI, blk = blockIdx.x % BPI;
  float mp = med[img * 2 + 0], my = med[img * 2 + 1];
  const float4* pb = p + (size_t)img * HW4;
  const float4* yb = y + (size_t)img * HW4;
  const int4* mb = m + (size_t)img * HW4;
  float sp = 0.f, sy = 0.f;
  for (int i = blk * 256 + threadIdx.x; i < HW4; i += BPI * 256) {
    float4 pv = pb[i], yv = yb[i];
    int4 mv = mb[i];
    if (mv.x) { sp += fabsf(pv.x - mp); sy += fabsf(yv.x - my); }
    if (mv.y) { sp += fabsf(pv.y - mp); sy += fabsf(yv.y - my); }
    if (mv.z) { sp += fabsf(pv.z - mp); sy += fabsf(yv.z - my); }
    if (mv.w) { sp += fabsf(pv.w - mp); sy += fabsf(yv.w - my); }
  }
  double dp = (double)sp, dy = (double)sy;
  for (int o = 32; o; o >>= 1) { dp += __shfl_down(dp, o, 64); dy += __shfl_down(dy, o, 64); }
  __shared__ double shp[4], shy[4];
  int lane = threadIdx.x & 63, wv = threadIdx.x >> 6;
  if (lane == 0) { shp[wv] = dp; shy[wv] = dy; }
  __syncthreads();
  if (threadIdx.x == 0) {
    atomicAdd(&absdev[img * 2 + 0], shp[0] + shp[1] + shp[2] + shp[3]);
    atomicAdd(&absdev[img * 2 + 1], shy[0] + shy[1] + shy[2] + shy[3]);
  }
}

__global__ void k_scinv(const double* __restrict__ absdev, const u32* __restrict__ cnt,
                        float* __restrict__ scinv)
{
  int t = threadIdx.x;
  if (t >= 128) return;
  u32 c = cnt[t >> 1];
  double sc = c ? (absdev[t] / (double)c + 1e-8) : 1e-8;
  scinv[t] = (float)(1.0 / sc);
}

// ---------- D = pred_hat - y_hat (all px) + masked |D| per image ----------
__global__ __launch_bounds__(256) void k_rho(const float4* __restrict__ p,
    const float4* __restrict__ y, const int4* __restrict__ m,
    const float* __restrict__ med, const float* __restrict__ scinv,
    float4* __restrict__ D, double* __restrict__ rho)
{
  int img = blockIdx.x / BPI, blk = blockIdx.x % BPI;
  float mp = med[img * 2 + 0], my = med[img * 2 + 1];
  float ap = scinv[img * 2 + 0], ay = scinv[img * 2 + 1];
  const float4* pb = p + (size_t)img * HW4;
  const float4* yb = y + (size_t)img * HW4;
  const int4* mb = m + (size_t)img * HW4;
  float4* Db = D + (size_t)img * HW4;
  float racc = 0.f;
  for (int i = blk * 256 + threadIdx.x; i < HW4; i += BPI * 256) {
    float4 pv = pb[i], yv = yb[i];
    int4 mv = mb[i];
    float4 d;
    d.x = (pv.x - mp) * ap - (yv.x - my) * ay;
    d.y = (pv.y - mp) * ap - (yv.y - my) * ay;
    d.z = (pv.z - mp) * ap - (yv.z - my) * ay;
    d.w = (pv.w - mp) * ap - (yv.w - my) * ay;
    if (mv.x) racc += fabsf(d.x);
    if (mv.y) racc += fabsf(d.y);
    if (mv.z) racc += fabsf(d.z);
    if (mv.w) racc += fabsf(d.w);
    Db[i] = d;
  }
  double dr = (double)racc;
  for (int o = 32; o; o >>= 1) dr += __shfl_down(dr, o, 64);
  __shared__ double sh[4];
  int lane = threadIdx.x & 63, wv = threadIdx.x >> 6;
  if (lane == 0) sh[wv] = dr;
  __syncthreads();
  if (threadIdx.x == 0) atomicAdd(&rho[img], sh[0] + sh[1] + sh[2] + sh[3]);
}

// ---------- masked gradient sums at one scale (MT = int for level 0, u8 pooled) ----------
template <typename MT>
__global__ __launch_bounds__(256) void k_grad(const float* __restrict__ D,
    const MT* __restrict__ M, int Wd, int Hd, int npix, double* __restrict__ gacc)
{
  float gx = 0.f, gy = 0.f;
  int cx = 0, cy = 0;
  int tot = NIMG * npix;
  for (int t = blockIdx.x * 256 + threadIdx.x; t < tot; t += gridDim.x * 256) {
    int img = t / npix;
    int px = t - img * npix;
    int row = px / Wd;
    int col = px - row * Wd;
    const float* Di = D + (size_t)img * npix;
    const MT* Mi = M + (size_t)img * npix;
    float dc = Di[px];
    bool mc = Mi[px] != 0;
    if (col + 1 < Wd && mc && Mi[px + 1]) { gx += fabsf(Di[px + 1] - dc); cx++; }
    if (row + 1 < Hd && mc && Mi[px + Wd]) { gy += fabsf(Di[px + Wd] - dc); cy++; }
  }
  double v0 = (double)gx, v1 = (double)cx, v2 = (double)gy, v3 = (double)cy;
  for (int o = 32; o; o >>= 1) {
    v0 += __shfl_down(v0, o, 64); v1 += __shfl_down(v1, o, 64);
    v2 += __shfl_down(v2, o, 64); v3 += __shfl_down(v3, o, 64);
  }
  __shared__ double sh[4][4];
  int lane = threadIdx.x & 63, wv = threadIdx.x >> 6;
  if (lane == 0) { sh[0][wv] = v0; sh[1][wv] = v1; sh[2][wv] = v2; sh[3][wv] = v3; }
  __syncthreads();
  if (threadIdx.x == 0) {
    atomicAdd(&gacc[0], sh[0][0] + sh[0][1] + sh[0][2] + sh[0][3]);
    atomicAdd(&gacc[1], sh[1][0] + sh[1][1] + sh[1][2] + sh[1][3]);
    atomicAdd(&gacc[2], sh[2][0] + sh[2][1] + sh[2][2] + sh[2][3]);
    atomicAdd(&gacc[3], sh[3][0] + sh[3][1] + sh[3][2] + sh[3][3]);
  }
}

// ---------- 2x2 avg pool of D + any-pool of mask ----------
template <typename MT>
__global__ __launch_bounds__(256) void k_pool(const float* __restrict__ Din,
    const MT* __restrict__ Min, float* __restrict__ Dout, u8* __restrict__ Mout,
    int Wi, int npi, int Wo, int npo)
{
  int t = blockIdx.x * 256 + threadIdx.x;
  int tot = NIMG * npo;
  if (t >= tot) return;
  int img = t / npo;
  int po = t - img * npo;
  int r = po / Wo, c = po - r * Wo;
  size_t base = (size_t)img * npi + (size_t)(2 * r) * Wi + 2 * c;
  const float* Di = Din + base;
  const MT* Mi = Min + base;
  Dout[t] = 0.25f * (Di[0] + Di[1] + Di[Wi] + Di[Wi + 1]);
  Mout[t] = (u8)(((Mi[0] != 0) | (Mi[1] != 0) | (Mi[Wi] != 0) | (Mi[Wi + 1] != 0)) ? 1 : 0);
}

// ---------- finalize scalar ----------
__global__ void k_final(const double* __restrict__ rho, const u32* __restrict__ cnt,
                        const double* __restrict__ gacc, float* __restrict__ out)
{
  if (threadIdx.x == 0 && blockIdx.x == 0) {
    double ssi = 0.0;
    for (int i = 0; i < NIMG; i++) {
      double c = cnt[i] ? (double)cnt[i] : 1.0;
      ssi += rho[i] / c;
    }
    ssi /= (double)NIMG;
    double g = 0.0;
    for (int s = 0; s < 4; s++) {
      double cx = gacc[s * 4 + 1], cy = gacc[s * 4 + 3];
      g += gacc[s * 4 + 0] / (cx > 1.0 ? cx : 1.0);
      g += gacc[s * 4 + 2] / (cy > 1.0 ? cy : 1.0);
    }
    g /= 4.0;
    out[0] = (float)(ssi + 0.5 * g);
  }
}

extern "C" void kernel_launch(void* const* d_in, const int* in_sizes, int n_in,
                              void* d_out, int out_size, void* d_ws, size_t ws_size,
                              hipStream_t stream) {
  (void)in_sizes; (void)n_in; (void)out_size; (void)ws_size;
  const float4* p4 = (const float4*)d_in[0];
  const float4* y4 = (const float4*)d_in[1];
  const int4* m4 = (const int4*)d_in[2];   // jax bool -> int32 per harness
  const int* m32 = (const int*)d_in[2];
  u8* ws = (u8*)d_ws;

  u32*    hist1 = (u32*)(ws + OFF_H1);
  u32*    hist2 = (u32*)(ws + OFF_H2);
  u32*    hist3 = (u32*)(ws + OFF_H3);
  u32*    cnt   = (u32*)(ws + OFF_CNT);
  u32*    selp  = (u32*)(ws + OFF_SELP);
  u32*    selr  = (u32*)(ws + OFF_SELR);
  float*  med   = (float*)(ws + OFF_MED);
  double* absd  = (double*)(ws + OFF_ABS);
  double* rho   = (double*)(ws + OFF_RHO);
  double* gacc  = (double*)(ws + OFF_GACC);
  float*  sci   = (float*)(ws + OFF_SCI);
  float*  D     = (float*)(ws + OFF_D);
  float*  P1    = (float*)(ws + OFF_P1);
  u8*     M1    = (u8*)(ws + OFF_M1);
  float*  P2    = (float*)(ws + OFF_P2);
  u8*     M2    = (u8*)(ws + OFF_M2);
  float*  P3    = (float*)(ws + OFF_P3);
  u8*     M3    = (u8*)(ws + OFF_M3);

  hipMemsetAsync(d_ws, 0, SMALL_END, stream);

  k_hist0<<<NIMG * BPI, 256, 0, stream>>>(p4, y4, m4, hist1, cnt);
  k_sel<<<128, 256, 0, stream>>>(hist1, cnt, selp, selr, med, 0, 2048);
  k_hist1<<<NIMG * BPI, 256, 0, stream>>>(p4, y4, m4, selp, hist2);
  k_sel<<<128, 256, 0, stream>>>(hist2, cnt, selp, selr, med, 1, 2048);
  k_hist2<<<NIMG * BPI, 256, 0, stream>>>(p4, y4, m4, selp, hist3);
  k_sel<<<128, 256, 0, stream>>>(hist3, cnt, selp, selr, med, 2, 1024);

  k_absdev<<<NIMG * BPI, 256, 0, stream>>>(p4, y4, m4, med, absd);
  k_scinv<<<1, 128, 0, stream>>>(absd, cnt, sci);
  k_rho<<<NIMG * BPI, 256, 0, stream>>>(p4, y4, m4, med, sci, (float4*)D, rho);

  k_grad<int><<<1024, 256, 0, stream>>>(D, m32, W0, H0, HW, gacc + 0);
  k_pool<int><<<(NIMG * N1 + 255) / 256, 256, 0, stream>>>(D, m32, P1, M1, W0, HW, W1, N1);
  k_grad<u8><<<512, 256, 0, stream>>>(P1, M1, W1, W1, N1, gacc + 4);
  k_pool<u8><<<(NIMG * N2 + 255) / 256, 256, 0, stream>>>(P1, M1, P2, M2, W1, N1, W2, N2);
  k_grad<u8><<<256, 256, 0, stream>>>(P2, M2, W2, W2, N2, gacc + 8);
  k_pool<u8><<<(NIMG * N3 + 255) / 256, 256, 0, stream>>>(P2, M2, P3, M3, W2, N2, W3, N3);
  k_grad<u8><<<64, 256, 0, stream>>>(P3, M3, W3, W3, N3, gacc + 12);

  k_final<<<1, 64, 0, stream>>>(rho, cnt, gacc, (float*)d_out);
}

// Round 3
// 571.672 us; speedup vs baseline: 1.1770x; 1.1770x over previous
//
#include <hip/hip_runtime.h>
#include <stdint.h>

typedef unsigned int u32;
typedef unsigned char u8;

#define NIMG 64
#define W0   518
#define H0   518
#define HW   268324
#define HW4  67081
#define BPI  16
#define NB0  33          // ceil(259/8) bands at scale 0

#define N1 67081         // 259x259
#define N2 16641         // 129x129
#define N3 4096          // 64x64

// ---- workspace byte offsets ----
#define OFF_H1   0ULL            // u32[64][2][2048]
#define OFF_H2   1048576ULL      // u32[64][2][2048]
#define OFF_H3   2097152ULL      // u32[64][2][1024]
#define OFF_HS3  2621440ULL      // double[64][2][1024]
#define OFF_CNT  3670016ULL      // u32[64]
#define OFF_SELP 3670272ULL      // u32[128]
#define OFF_SELR 3670784ULL      // u32[128]
#define OFF_NLT  3671296ULL      // u32[128]
#define OFF_STOT 3671808ULL      // double[128]
#define OFF_SLT  3672832ULL      // double[128]
#define OFF_MED  3673856ULL      // float[128]
#define OFF_SCI  3674368ULL      // float[128]
#define OFF_RHO  3674880ULL      // double[64]
#define OFF_GACC 3675392ULL      // double[16]
#define SMALL_END 3675520ULL
#define OFF_MU8  3675648ULL                    // u8[64*268324]
#define OFF_P1   (OFF_MU8 + 17172736ULL)       // float[64*67081]
#define OFF_M1   (OFF_P1 + 17172736ULL)        // u8[64*67081]
#define OFF_P2   (OFF_M1 + 4293184ULL)         // float[64*16641]
#define OFF_M2   (OFF_P2 + 4260096ULL)         // u8[64*16641]
#define OFF_P3   (OFF_M2 + 1065024ULL)         // float[64*4096]
#define OFF_M3   (OFF_P3 + 1048576ULL)         // u8[64*4096]

__device__ __forceinline__ u32 f2key(float f) {
  u32 u = __float_as_uint(f);
  return (u & 0x80000000u) ? ~u : (u | 0x80000000u);
}
__device__ __forceinline__ float key2f(u32 k) {
  u32 u = (k & 0x80000000u) ? (k & 0x7fffffffu) : ~k;
  return __uint_as_float(u);
}

// ---------- pass 0: count + top-11-bit histogram + u8 mask write ----------
__global__ __launch_bounds__(256) void k_hist0(const float4* __restrict__ p,
    const float4* __restrict__ y, const int4* __restrict__ m,
    uchar4* __restrict__ mu4, u32* __restrict__ hist, u32* __restrict__ cnt)
{
  __shared__ u32 h[4096];
  __shared__ u32 blkcnt;
  for (int i = threadIdx.x; i < 4096; i += 256) h[i] = 0;
  if (threadIdx.x == 0) blkcnt = 0;
  __syncthreads();
  int img = blockIdx.x / BPI, blk = blockIdx.x % BPI;
  const float4* pb = p + (size_t)img * HW4;
  const float4* yb = y + (size_t)img * HW4;
  const int4* mb = m + (size_t)img * HW4;
  uchar4* mo = mu4 + (size_t)img * HW4;
  int lc = 0;
  for (int i = blk * 256 + threadIdx.x; i < HW4; i += BPI * 256) {
    float4 pv = pb[i], yv = yb[i];
    int4 mv = mb[i];
    uchar4 mw;
    mw.x = mv.x ? 1 : 0; mw.y = mv.y ? 1 : 0; mw.z = mv.z ? 1 : 0; mw.w = mv.w ? 1 : 0;
    mo[i] = mw;
#define H0C(mm, pp, yy) if (mm) { lc++; atomicAdd(&h[f2key(pp) >> 21], 1u); atomicAdd(&h[2048u + (f2key(yy) >> 21)], 1u); }
    H0C(mw.x, pv.x, yv.x) H0C(mw.y, pv.y, yv.y) H0C(mw.z, pv.z, yv.z) H0C(mw.w, pv.w, yv.w)
#undef H0C
  }
  atomicAdd(&blkcnt, (u32)lc);
  __syncthreads();
  u32* gh = hist + (size_t)img * 4096;
  for (int b = threadIdx.x; b < 4096; b += 256) if (h[b]) atomicAdd(&gh[b], h[b]);
  if (threadIdx.x == 0) atomicAdd(&cnt[img], blkcnt);
}

// ---------- pass 1: mid-11-bit hist within L0 bin + S_total + S_lt(L0) ----------
__global__ __launch_bounds__(256) void k_hist1(const float4* __restrict__ p,
    const float4* __restrict__ y, const uchar4* __restrict__ mu,
    const u32* __restrict__ selp, u32* __restrict__ hist,
    double* __restrict__ Stot, double* __restrict__ Slt)
{
  __shared__ u32 h[4096];
  for (int i = threadIdx.x; i < 4096; i += 256) h[i] = 0;
  __syncthreads();
  int img = blockIdx.x / BPI, blk = blockIdx.x % BPI;
  u32 binP = selp[img * 2 + 0], binY = selp[img * 2 + 1];
  const float4* pb = p + (size_t)img * HW4;
  const float4* yb = y + (size_t)img * HW4;
  const uchar4* mb = mu + (size_t)img * HW4;
  float sAp = 0.f, sLp = 0.f, sAy = 0.f, sLy = 0.f;
  for (int i = blk * 256 + threadIdx.x; i < HW4; i += BPI * 256) {
    float4 pv = pb[i], yv = yb[i];
    uchar4 mv = mb[i];
#define H1C(mm, pv_, yv_) if (mm) { \
      float v = pv_; u32 k = f2key(v); u32 tb = k >> 21; sAp += v; \
      if (tb < binP) sLp += v; else if (tb == binP) atomicAdd(&h[(k >> 10) & 0x7FFu], 1u); \
      v = yv_; k = f2key(v); tb = k >> 21; sAy += v; \
      if (tb < binY) sLy += v; else if (tb == binY) atomicAdd(&h[2048u + ((k >> 10) & 0x7FFu)], 1u); }
    H1C(mv.x, pv.x, yv.x) H1C(mv.y, pv.y, yv.y) H1C(mv.z, pv.z, yv.z) H1C(mv.w, pv.w, yv.w)
#undef H1C
  }
  double v0 = (double)sAp, v1 = (double)sLp, v2 = (double)sAy, v3 = (double)sLy;
  for (int o = 32; o; o >>= 1) {
    v0 += __shfl_down(v0, o, 64); v1 += __shfl_down(v1, o, 64);
    v2 += __shfl_down(v2, o, 64); v3 += __shfl_down(v3, o, 64);
  }
  __shared__ double sh[4][4];
  int lane = threadIdx.x & 63, wv = threadIdx.x >> 6;
  if (lane == 0) { sh[0][wv] = v0; sh[1][wv] = v1; sh[2][wv] = v2; sh[3][wv] = v3; }
  __syncthreads();
  if (threadIdx.x == 0) {
    atomicAdd(&Stot[img * 2 + 0], sh[0][0] + sh[0][1] + sh[0][2] + sh[0][3]);
    atomicAdd(&Slt [img * 2 + 0], sh[1][0] + sh[1][1] + sh[1][2] + sh[1][3]);
    atomicAdd(&Stot[img * 2 + 1], sh[2][0] + sh[2][1] + sh[2][2] + sh[2][3]);
    atomicAdd(&Slt [img * 2 + 1], sh[3][0] + sh[3][1] + sh[3][2] + sh[3][3]);
  }
  __syncthreads();
  u32* gh = hist + (size_t)img * 4096;
  for (int b = threadIdx.x; b < 4096; b += 256) if (h[b]) atomicAdd(&gh[b], h[b]);
}

// ---------- pass 2: low-10-bit hist + per-bin value sums + S_lt(L1) ----------
__global__ __launch_bounds__(256) void k_hist2(const float4* __restrict__ p,
    const float4* __restrict__ y, const uchar4* __restrict__ mu,
    const u32* __restrict__ selp, u32* __restrict__ hist,
    double* __restrict__ hsum, double* __restrict__ Slt)
{
  __shared__ u32 h[2048];
  __shared__ float fs[2048];
  for (int i = threadIdx.x; i < 2048; i += 256) { h[i] = 0; fs[i] = 0.f; }
  __syncthreads();
  int img = blockIdx.x / BPI, blk = blockIdx.x % BPI;
  u32 prP = selp[img * 2 + 0], prY = selp[img * 2 + 1];   // 22-bit prefixes
  u32 topP = prP >> 11, topY = prY >> 11;
  const float4* pb = p + (size_t)img * HW4;
  const float4* yb = y + (size_t)img * HW4;
  const uchar4* mb = mu + (size_t)img * HW4;
  float sLp = 0.f, sLy = 0.f;
  for (int i = blk * 256 + threadIdx.x; i < HW4; i += BPI * 256) {
    float4 pv = pb[i], yv = yb[i];
    uchar4 mv = mb[i];
#define H2C(mm, pv_, yv_) if (mm) { \
      float v = pv_; u32 k = f2key(v); u32 kp = k >> 10; \
      if (kp == prP) { atomicAdd(&h[k & 0x3FFu], 1u); atomicAdd(&fs[k & 0x3FFu], v); } \
      else if (kp < prP && (k >> 21) == topP) sLp += v; \
      v = yv_; k = f2key(v); kp = k >> 10; \
      if (kp == prY) { atomicAdd(&h[1024u + (k & 0x3FFu)], 1u); atomicAdd(&fs[1024u + (k & 0x3FFu)], v); } \
      else if (kp < prY && (k >> 21) == topY) sLy += v; }
    H2C(mv.x, pv.x, yv.x) H2C(mv.y, pv.y, yv.y) H2C(mv.z, pv.z, yv.z) H2C(mv.w, pv.w, yv.w)
#undef H2C
  }
  double v0 = (double)sLp, v1 = (double)sLy;
  for (int o = 32; o; o >>= 1) {
    v0 += __shfl_down(v0, o, 64); v1 += __shfl_down(v1, o, 64);
  }
  __shared__ double sh[2][4];
  int lane = threadIdx.x & 63, wv = threadIdx.x >> 6;
  if (lane == 0) { sh[0][wv] = v0; sh[1][wv] = v1; }
  __syncthreads();
  if (threadIdx.x == 0) {
    atomicAdd(&Slt[img * 2 + 0], sh[0][0] + sh[0][1] + sh[0][2] + sh[0][3]);
    atomicAdd(&Slt[img * 2 + 1], sh[1][0] + sh[1][1] + sh[1][2] + sh[1][3]);
  }
  __syncthreads();
  u32* gh = hist + (size_t)img * 2048;
  double* gs = hsum + (size_t)img * 2048;
  for (int b = threadIdx.x; b < 2048; b += 256)
    if (h[b]) { atomicAdd(&gh[b], h[b]); atomicAdd(&gs[b], (double)fs[b]); }
}

// ---------- select passes 0/1 (2048 bins) ----------
__global__ __launch_bounds__(256) void k_sel01(const u32* __restrict__ hist,
    const u32* __restrict__ cnt, u32* __restrict__ selp, u32* __restrict__ selr,
    u32* __restrict__ nlt, int pass)
{
  int t = blockIdx.x, img = t >> 1;
  const u32* hh = hist + (size_t)t * 2048;
  u32 c = cnt[img];
  u32 target = (pass == 0) ? (c ? ((c - 1) >> 1) : 0u) : selr[t];
  int b0 = threadIdx.x * 8;
  u32 loc[8]; u32 s = 0;
  for (int j = 0; j < 8; j++) { loc[j] = hh[b0 + j]; s += loc[j]; }
  __shared__ u32 ps[256];
  ps[threadIdx.x] = s;
  __syncthreads();
  for (int off = 1; off < 256; off <<= 1) {
    u32 v = (threadIdx.x >= (u32)off) ? ps[threadIdx.x - off] : 0u;
    __syncthreads();
    ps[threadIdx.x] += v;
    __syncthreads();
  }
  u32 cum = ps[threadIdx.x] - s;
  for (int j = 0; j < 8; j++) {
    u32 v = loc[j];
    if (c && target >= cum && target < cum + v) {
      u32 bin = (u32)(b0 + j);
      selp[t] = (pass == 0) ? bin : ((selp[t] << 11) | bin);
      selr[t] = target - cum;
      nlt[t] += cum;
    }
    cum += v;
  }
}

// ---------- select pass 2 (1024 bins) + median + scale ----------
__global__ __launch_bounds__(256) void k_selC(const u32* __restrict__ hist,
    const double* __restrict__ hsum, const u32* __restrict__ cnt,
    const u32* __restrict__ selp, const u32* __restrict__ selr,
    const u32* __restrict__ nlt, const double* __restrict__ Stot,
    const double* __restrict__ Slt, float* __restrict__ med, float* __restrict__ sci)
{
  int t = blockIdx.x, img = t >> 1;
  const u32* hh = hist + (size_t)t * 1024;
  const double* hs = hsum + (size_t)t * 1024;
  u32 c = cnt[img];
  u32 target = selr[t];
  int b0 = threadIdx.x * 4;
  u32 loc[4]; double locs[4];
  u32 s = 0; double sd = 0.0;
  for (int j = 0; j < 4; j++) { loc[j] = hh[b0 + j]; locs[j] = hs[b0 + j]; s += loc[j]; sd += locs[j]; }
  __shared__ u32 ps[256];
  __shared__ double psd[256];
  ps[threadIdx.x] = s; psd[threadIdx.x] = sd;
  __syncthreads();
  for (int off = 1; off < 256; off <<= 1) {
    u32 v = (threadIdx.x >= (u32)off) ? ps[threadIdx.x - off] : 0u;
    double vd = (threadIdx.x >= (u32)off) ? psd[threadIdx.x - off] : 0.0;
    __syncthreads();
    ps[threadIdx.x] += v; psd[threadIdx.x] += vd;
    __syncthreads();
  }
  u32 cum = ps[threadIdx.x] - s;
  double cumd = psd[threadIdx.x] - sd;
  for (int j = 0; j < 4; j++) {
    u32 v = loc[j];
    if (c && target >= cum && target < cum + v) {
      u32 key = (selp[t] << 10) | (u32)(b0 + j);
      double m = (double)key2f(key);
      double nltT = (double)(nlt[t] + cum);
      double sltT = Slt[t] + cumd;
      double S = Stot[t];
      double mad = S + 2.0 * m * nltT - 2.0 * sltT - m * (double)c;
      double sc = mad / (double)c + 1e-8;
      med[t] = (float)m;
      sci[t] = (float)(1.0 / sc);
    }
    cum += v; cumd += locs[j];
  }
  if (c == 0 && threadIdx.x == 0) { med[t] = 0.0f; sci[t] = 1e8f; }
}

// ---------- fused: D in registers + rho + scale-0 grad + pool0 ----------
__global__ __launch_bounds__(256) void k_fuse0(const float* __restrict__ p,
    const float* __restrict__ y, const u8* __restrict__ mu,
    const float* __restrict__ med, const float* __restrict__ sci,
    float* __restrict__ P1, u8* __restrict__ M1,
    double* __restrict__ rho, double* __restrict__ gacc)
{
  int img = blockIdx.x / NB0, band = blockIdx.x % NB0;
  float mp = med[img * 2 + 0], my = med[img * 2 + 1];
  float ap = sci[img * 2 + 0], ay = sci[img * 2 + 1];
  const float* pb = p + (size_t)img * HW;
  const float* yb = y + (size_t)img * HW;
  const u8*   mb = mu + (size_t)img * HW;
  int ra = band * 16;
  int rb = min(ra + 16, H0);
  int rend = (rb < H0) ? rb + 1 : H0;
  float gx = 0.f, gy = 0.f, rr = 0.f;
  int cx = 0, cy = 0;
  float pd0[2], pd1[2];
  u8 pm0[2], pm1[2];
  for (int r = ra; r < rend; ++r) {
    bool core = r < rb;
    int base = r * W0;
#pragma unroll
    for (int s = 0; s < 2; ++s) {
      int oc = threadIdx.x + s * 256;
      if (oc < 259) {
        int c0 = 2 * oc, c1 = c0 + 1, cn = c0 + 2;
        float d0 = (pb[base + c0] - mp) * ap - (yb[base + c0] - my) * ay;
        float d1 = (pb[base + c1] - mp) * ap - (yb[base + c1] - my) * ay;
        u8 m0 = mb[base + c0], m1 = mb[base + c1];
        if (core) {
          if (m0 & m1) { gx += fabsf(d1 - d0); cx++; }
          if (cn < W0) {
            float dn = (pb[base + cn] - mp) * ap - (yb[base + cn] - my) * ay;
            u8 mn = mb[base + cn];
            if (m1 & mn) { gx += fabsf(dn - d1); cx++; }
          }
          if (m0) rr += fabsf(d0);
          if (m1) rr += fabsf(d1);
        }
        if (r > ra) {
          if (m0 & pm0[s]) { gy += fabsf(d0 - pd0[s]); cy++; }
          if (m1 & pm1[s]) { gy += fabsf(d1 - pd1[s]); cy++; }
        }
        if (core && (r & 1)) {
          size_t o = (size_t)img * N1 + (size_t)(r >> 1) * 259 + oc;
          P1[o] = 0.25f * (pd0[s] + pd1[s] + d0 + d1);
          M1[o] = (u8)((pm0[s] | pm1[s] | m0 | m1) ? 1 : 0);
        }
        pd0[s] = d0; pd1[s] = d1; pm0[s] = m0; pm1[s] = m1;
      }
    }
  }
  double v0 = (double)gx, v1 = (double)cx, v2 = (double)gy, v3 = (double)cy, v4 = (double)rr;
  for (int o = 32; o; o >>= 1) {
    v0 += __shfl_down(v0, o, 64); v1 += __shfl_down(v1, o, 64);
    v2 += __shfl_down(v2, o, 64); v3 += __shfl_down(v3, o, 64);
    v4 += __shfl_down(v4, o, 64);
  }
  __shared__ double sh[5][4];
  int lane = threadIdx.x & 63, wv = threadIdx.x >> 6;
  if (lane == 0) { sh[0][wv] = v0; sh[1][wv] = v1; sh[2][wv] = v2; sh[3][wv] = v3; sh[4][wv] = v4; }
  __syncthreads();
  if (threadIdx.x == 0) {
    atomicAdd(&gacc[0], sh[0][0] + sh[0][1] + sh[0][2] + sh[0][3]);
    atomicAdd(&gacc[1], sh[1][0] + sh[1][1] + sh[1][2] + sh[1][3]);
    atomicAdd(&gacc[2], sh[2][0] + sh[2][1] + sh[2][2] + sh[2][3]);
    atomicAdd(&gacc[3], sh[3][0] + sh[3][1] + sh[3][2] + sh[3][3]);
    atomicAdd(&rho[img], sh[4][0] + sh[4][1] + sh[4][2] + sh[4][3]);
  }
}

// ---------- generic grad+pool for scales 1,2 (Wout <= 256) ----------
__global__ __launch_bounds__(256) void k_gp(const float* __restrict__ Pin,
    const u8* __restrict__ Min, float* __restrict__ Pout, u8* __restrict__ Mout,
    int Win, int Hin, int Wout, int Hout, int nb, double* __restrict__ gaccS)
{
  int img = blockIdx.x / nb, band = blockIdx.x % nb;
  int npixI = Win * Hin, npixO = Wout * Hout;
  const float* pb = Pin + (size_t)img * npixI;
  const u8* mb = Min + (size_t)img * npixI;
  int poolEnd = 2 * Hout;
  int ra = band * 16;
  int rb = min(ra + 16, poolEnd);
  int rbx = (band == nb - 1) ? Hin : rb;
  int rend = (rbx < Hin) ? rbx + 1 : Hin;
  float gx = 0.f, gy = 0.f;
  int cx = 0, cy = 0;
  int oc = threadIdx.x;
  if (oc < Wout) {
    int c0 = 2 * oc, c1 = c0 + 1, cn = c0 + 2;
    bool vn = cn < Win;
    bool gyn = vn && (cn >= 2 * Wout);   // odd-W last column (nobody's primary)
    float pd0 = 0.f, pd1 = 0.f, pdn = 0.f;
    u8 pm0 = 0, pm1 = 0, pmn = 0;
    for (int r = ra; r < rend; ++r) {
      bool core = r < rbx;
      int base = r * Win;
      float d0 = pb[base + c0], d1 = pb[base + c1];
      u8 m0 = mb[base + c0], m1 = mb[base + c1];
      float dn = 0.f; u8 mn = 0;
      if (vn) { dn = pb[base + cn]; mn = mb[base + cn]; }
      if (core) {
        if (m0 & m1) { gx += fabsf(d1 - d0); cx++; }
        if (vn && (m1 & mn)) { gx += fabsf(dn - d1); cx++; }
      }
      if (r > ra) {
        if (m0 & pm0) { gy += fabsf(d0 - pd0); cy++; }
        if (m1 & pm1) { gy += fabsf(d1 - pd1); cy++; }
        if (gyn && (mn & pmn)) { gy += fabsf(dn - pdn); cy++; }
      }
      if (core && (r & 1) && r < poolEnd) {
        size_t o = (size_t)img * npixO + (size_t)(r >> 1) * Wout + oc;
        Pout[o] = 0.25f * (pd0 + pd1 + d0 + d1);
        Mout[o] = (u8)((pm0 | pm1 | m0 | m1) ? 1 : 0);
      }
      pd0 = d0; pd1 = d1; pdn = dn; pm0 = m0; pm1 = m1; pmn = mn;
    }
  }
  double v0 = (double)gx, v1 = (double)cx, v2 = (double)gy, v3 = (double)cy;
  for (int o = 32; o; o >>= 1) {
    v0 += __shfl_down(v0, o, 64); v1 += __shfl_down(v1, o, 64);
    v2 += __shfl_down(v2, o, 64); v3 += __shfl_down(v3, o, 64);
  }
  __shared__ double sh[4][4];
  int lane = threadIdx.x & 63, wv = threadIdx.x >> 6;
  if (lane == 0) { sh[0][wv] = v0; sh[1][wv] = v1; sh[2][wv] = v2; sh[3][wv] = v3; }
  __syncthreads();
  if (threadIdx.x == 0) {
    atomicAdd(&gaccS[0], sh[0][0] + sh[0][1] + sh[0][2] + sh[0][3]);
    atomicAdd(&gaccS[1], sh[1][0] + sh[1][1] + sh[1][2] + sh[1][3]);
    atomicAdd(&gaccS[2], sh[2][0] + sh[2][1] + sh[2][2] + sh[2][3]);
    atomicAdd(&gaccS[3], sh[3][0] + sh[3][1] + sh[3][2] + sh[3][3]);
  }
}

// ---------- scale-3 gradient (64x64, shift/mask indexing) ----------
__global__ __launch_bounds__(256) void k_grad3(const float* __restrict__ P,
    const u8* __restrict__ M, double* __restrict__ gaccS)
{
  int t = blockIdx.x * 256 + threadIdx.x;   // < 64*4096
  int img = t >> 12, px = t & 4095;
  int col = px & 63;
  const float* Pi = P + ((size_t)img << 12);
  const u8* Mi = M + ((size_t)img << 12);
  float gx = 0.f, gy = 0.f;
  int cx = 0, cy = 0;
  float dc = Pi[px];
  u8 mc = Mi[px];
  if (col < 63 && mc && Mi[px + 1]) { gx = fabsf(Pi[px + 1] - dc); cx = 1; }
  if (px < 4032 && mc && Mi[px + 64]) { gy = fabsf(Pi[px + 64] - dc); cy = 1; }
  double v0 = (double)gx, v1 = (double)cx, v2 = (double)gy, v3 = (double)cy;
  for (int o = 32; o; o >>= 1) {
    v0 += __shfl_down(v0, o, 64); v1 += __shfl_down(v1, o, 64);
    v2 += __shfl_down(v2, o, 64); v3 += __shfl_down(v3, o, 64);
  }
  __shared__ double sh[4][4];
  int lane = threadIdx.x & 63, wv = threadIdx.x >> 6;
  if (lane == 0) { sh[0][wv] = v0; sh[1][wv] = v1; sh[2][wv] = v2; sh[3][wv] = v3; }
  __syncthreads();
  if (threadIdx.x == 0) {
    atomicAdd(&gaccS[0], sh[0][0] + sh[0][1] + sh[0][2] + sh[0][3]);
    atomicAdd(&gaccS[1], sh[1][0] + sh[1][1] + sh[1][2] + sh[1][3]);
    atomicAdd(&gaccS[2], sh[2][0] + sh[2][1] + sh[2][2] + sh[2][3]);
    atomicAdd(&gaccS[3], sh[3][0] + sh[3][1] + sh[3][2] + sh[3][3]);
  }
}

// ---------- finalize scalar ----------
__global__ void k_final(const double* __restrict__ rho, const u32* __restrict__ cnt,
                        const double* __restrict__ gacc, float* __restrict__ out)
{
  if (threadIdx.x == 0 && blockIdx.x == 0) {
    double ssi = 0.0;
    for (int i = 0; i < NIMG; i++) {
      double c = cnt[i] ? (double)cnt[i] : 1.0;
      ssi += rho[i] / c;
    }
    ssi /= (double)NIMG;
    double g = 0.0;
    for (int s = 0; s < 4; s++) {
      double cx = gacc[s * 4 + 1], cy = gacc[s * 4 + 3];
      g += gacc[s * 4 + 0] / (cx > 1.0 ? cx : 1.0);
      g += gacc[s * 4 + 2] / (cy > 1.0 ? cy : 1.0);
    }
    g /= 4.0;
    out[0] = (float)(ssi + 0.5 * g);
  }
}

extern "C" void kernel_launch(void* const* d_in, const int* in_sizes, int n_in,
                              void* d_out, int out_size, void* d_ws, size_t ws_size,
                              hipStream_t stream) {
  (void)in_sizes; (void)n_in; (void)out_size; (void)ws_size;
  const float4* p4 = (const float4*)d_in[0];
  const float4* y4 = (const float4*)d_in[1];
  const int4* m4 = (const int4*)d_in[2];
  const float* pf = (const float*)d_in[0];
  const float* yf = (const float*)d_in[1];
  u8* ws = (u8*)d_ws;

  u32*    H1   = (u32*)(ws + OFF_H1);
  u32*    H2   = (u32*)(ws + OFF_H2);
  u32*    H3   = (u32*)(ws + OFF_H3);
  double* HS3  = (double*)(ws + OFF_HS3);
  u32*    cnt  = (u32*)(ws + OFF_CNT);
  u32*    selp = (u32*)(ws + OFF_SELP);
  u32*    selr = (u32*)(ws + OFF_SELR);
  u32*    nlt  = (u32*)(ws + OFF_NLT);
  double* Stot = (double*)(ws + OFF_STOT);
  double* Slt  = (double*)(ws + OFF_SLT);
  float*  med  = (float*)(ws + OFF_MED);
  float*  sci  = (float*)(ws + OFF_SCI);
  double* rho  = (double*)(ws + OFF_RHO);
  double* gacc = (double*)(ws + OFF_GACC);
  u8*     mu8  = (u8*)(ws + OFF_MU8);
  float*  P1   = (float*)(ws + OFF_P1);
  u8*     M1   = (u8*)(ws + OFF_M1);
  float*  P2   = (float*)(ws + OFF_P2);
  u8*     M2   = (u8*)(ws + OFF_M2);
  float*  P3   = (float*)(ws + OFF_P3);
  u8*     M3   = (u8*)(ws + OFF_M3);

  hipMemsetAsync(d_ws, 0, SMALL_END, stream);

  k_hist0<<<NIMG * BPI, 256, 0, stream>>>(p4, y4, m4, (uchar4*)mu8, H1, cnt);
  k_sel01<<<128, 256, 0, stream>>>(H1, cnt, selp, selr, nlt, 0);
  k_hist1<<<NIMG * BPI, 256, 0, stream>>>(p4, y4, (const uchar4*)mu8, selp, H2, Stot, Slt);
  k_sel01<<<128, 256, 0, stream>>>(H2, cnt, selp, selr, nlt, 1);
  k_hist2<<<NIMG * BPI, 256, 0, stream>>>(p4, y4, (const uchar4*)mu8, selp, H3, HS3, Slt);
  k_selC<<<128, 256, 0, stream>>>(H3, HS3, cnt, selp, selr, nlt, Stot, Slt, med, sci);

  k_fuse0<<<NIMG * NB0, 256, 0, stream>>>(pf, yf, mu8, med, sci, P1, M1, rho, gacc);
  k_gp<<<NIMG * 17, 256, 0, stream>>>(P1, M1, P2, M2, 259, 259, 129, 129, 17, gacc + 4);
  k_gp<<<NIMG * 8, 256, 0, stream>>>(P2, M2, P3, M3, 129, 129, 64, 64, 8, gacc + 8);
  k_grad3<<<1024, 256, 0, stream>>>(P3, M3, gacc + 12);

  k_final<<<1, 64, 0, stream>>>(rho, cnt, gacc, (float*)d_out);
}

// Round 4
// 522.670 us; speedup vs baseline: 1.2873x; 1.0938x over previous
//
#include <hip/hip_runtime.h>
#include <stdint.h>

typedef unsigned int u32;
typedef unsigned char u8;

#define NIMG 64
#define W0   518
#define H0   518
#define HW   268324
#define HW4  67081
#define BPI  32          // blocks per image for full scans (64*32*4 waves = 8192 = device capacity)
#define NB0  33          // bands of 16 rows at scale 0
#define N1 67081         // 259x259
#define N2 16641         // 129x129
#define N3 4096          // 64x64
#define CAP 32768        // candidate capacity per (img,arr); expected ~1e2

// ---- workspace byte offsets ----
#define OFF_HG   0ULL            // u32[64][2][2048] L0 histogram
#define OFF_CNT  1048576ULL      // u32[64]
#define OFF_SELP 1048832ULL      // u32[128]
#define OFF_SELR 1049344ULL      // u32[128]
#define OFF_NLT  1049856ULL      // u32[128]
#define OFF_STOT 1050368ULL      // double[128]
#define OFF_SLT  1051392ULL      // double[128]
#define OFF_MED  1052416ULL      // float[128]
#define OFF_SCI  1052928ULL      // float[128]
#define OFF_RHO  1053440ULL      // double[64]
#define OFF_GACC 1053952ULL      // double[16]
#define OFF_CCNT 1054080ULL      // u32[128]
#define SMALL_END 1054592ULL
#define OFF_CAND 1054592ULL                    // float[128][CAP] = 16 MB
#define OFF_MU8  (OFF_CAND + 16777216ULL)      // u8[64*268324]
#define OFF_P1   (OFF_MU8 + 17172736ULL)       // float[64*67081]
#define OFF_M1   (OFF_P1 + 17172736ULL)        // u8[64*67081]
#define OFF_P2   (OFF_M1 + 4293184ULL)         // float[64*16641]
#define OFF_M2   (OFF_P2 + 4260096ULL)         // u8[64*16641]
#define OFF_P3   (OFF_M2 + 1065024ULL)         // float[64*4096]
#define OFF_M3   (OFF_P3 + 1048576ULL)         // u8[64*4096]

__device__ __forceinline__ u32 f2key(float f) {
  u32 u = __float_as_uint(f);
  return (u & 0x80000000u) ? ~u : (u | 0x80000000u);
}
__device__ __forceinline__ float key2f(u32 k) {
  u32 u = (k & 0x80000000u) ? (k & 0x7fffffffu) : ~k;
  return __uint_as_float(u);
}

// ---------- pass 0: count + top-11-bit histogram + u8 mask write ----------
__global__ __launch_bounds__(256) void k_hist0(const float4* __restrict__ p,
    const float4* __restrict__ y, const int4* __restrict__ m,
    uchar4* __restrict__ mu4, u32* __restrict__ hist, u32* __restrict__ cnt)
{
  __shared__ u32 h[4096];
  __shared__ u32 blkcnt;
  for (int i = threadIdx.x; i < 4096; i += 256) h[i] = 0;
  if (threadIdx.x == 0) blkcnt = 0;
  __syncthreads();
  int img = blockIdx.x / BPI, blk = blockIdx.x % BPI;
  const float4* pb = p + (size_t)img * HW4;
  const float4* yb = y + (size_t)img * HW4;
  const int4* mb = m + (size_t)img * HW4;
  uchar4* mo = mu4 + (size_t)img * HW4;
  int lc = 0;
  for (int i = blk * 256 + threadIdx.x; i < HW4; i += BPI * 256) {
    float4 pv = pb[i], yv = yb[i];
    int4 mv = mb[i];
    uchar4 mw;
    mw.x = mv.x ? 1 : 0; mw.y = mv.y ? 1 : 0; mw.z = mv.z ? 1 : 0; mw.w = mv.w ? 1 : 0;
    mo[i] = mw;
#define H0C(mm, pp, yy) if (mm) { lc++; atomicAdd(&h[f2key(pp) >> 21], 1u); atomicAdd(&h[2048u + (f2key(yy) >> 21)], 1u); }
    H0C(mw.x, pv.x, yv.x) H0C(mw.y, pv.y, yv.y) H0C(mw.z, pv.z, yv.z) H0C(mw.w, pv.w, yv.w)
#undef H0C
  }
  atomicAdd(&blkcnt, (u32)lc);
  __syncthreads();
  u32* gh = hist + (size_t)img * 4096;
  for (int b = threadIdx.x; b < 4096; b += 256) if (h[b]) atomicAdd(&gh[b], h[b]);
  if (threadIdx.x == 0) atomicAdd(&cnt[img], blkcnt);
}

// ---------- select L0 bin: one block per (img,arr) ----------
__global__ __launch_bounds__(256) void k_sel0(const u32* __restrict__ hist,
    const u32* __restrict__ cnt, u32* __restrict__ selp, u32* __restrict__ selr,
    u32* __restrict__ nlt)
{
  int t = blockIdx.x, img = t >> 1;
  const u32* hh = hist + (size_t)t * 2048;
  u32 c = cnt[img];
  u32 target = c ? ((c - 1) >> 1) : 0u;
  int b0 = threadIdx.x * 8;
  u32 loc[8]; u32 s = 0;
  for (int j = 0; j < 8; j++) { loc[j] = hh[b0 + j]; s += loc[j]; }
  __shared__ u32 ps[256];
  ps[threadIdx.x] = s;
  __syncthreads();
  for (int off = 1; off < 256; off <<= 1) {
    u32 v = (threadIdx.x >= (u32)off) ? ps[threadIdx.x - off] : 0u;
    __syncthreads();
    ps[threadIdx.x] += v;
    __syncthreads();
  }
  u32 cum = ps[threadIdx.x] - s;
  for (int j = 0; j < 8; j++) {
    u32 v = loc[j];
    if (c && target >= cum && target < cum + v) {
      selp[t] = (u32)(b0 + j);
      selr[t] = target - cum;
      nlt[t] = cum;
    }
    cum += v;
  }
}

// ---------- compact: stream p,y once; S_total, S_below-bin, append bin members ----------
__global__ __launch_bounds__(256) void k_compact(const float4* __restrict__ p,
    const float4* __restrict__ y, const uchar4* __restrict__ mu,
    const u32* __restrict__ selp, float* __restrict__ cand, u32* __restrict__ ccnt,
    double* __restrict__ Stot, double* __restrict__ Slt)
{
  int img = blockIdx.x / BPI, blk = blockIdx.x % BPI;
  u32 binP = selp[img * 2 + 0], binY = selp[img * 2 + 1];
  const float4* pb = p + (size_t)img * HW4;
  const float4* yb = y + (size_t)img * HW4;
  const uchar4* mb = mu + (size_t)img * HW4;
  float* cp = cand + (size_t)(img * 2 + 0) * CAP;
  float* cyv = cand + (size_t)(img * 2 + 1) * CAP;
  u32* ccP = &ccnt[img * 2 + 0];
  u32* ccY = &ccnt[img * 2 + 1];
  float sAp = 0.f, sLp = 0.f, sAy = 0.f, sLy = 0.f;
  for (int i = blk * 256 + threadIdx.x; i < HW4; i += BPI * 256) {
    float4 pv = pb[i], yv = yb[i];
    uchar4 mv = mb[i];
#define CC(mm, pv_, yv_) if (mm) { \
      float v = pv_; u32 b = f2key(v) >> 21; sAp += v; \
      if (b < binP) sLp += v; else if (b == binP) { u32 ix = atomicAdd(ccP, 1u); if (ix < CAP) cp[ix] = v; } \
      v = yv_; b = f2key(v) >> 21; sAy += v; \
      if (b < binY) sLy += v; else if (b == binY) { u32 ix = atomicAdd(ccY, 1u); if (ix < CAP) cyv[ix] = v; } }
    CC(mv.x, pv.x, yv.x) CC(mv.y, pv.y, yv.y) CC(mv.z, pv.z, yv.z) CC(mv.w, pv.w, yv.w)
#undef CC
  }
  double v0 = (double)sAp, v1 = (double)sLp, v2 = (double)sAy, v3 = (double)sLy;
  for (int o = 32; o; o >>= 1) {
    v0 += __shfl_down(v0, o, 64); v1 += __shfl_down(v1, o, 64);
    v2 += __shfl_down(v2, o, 64); v3 += __shfl_down(v3, o, 64);
  }
  __shared__ double sh[4][4];
  int lane = threadIdx.x & 63, wv = threadIdx.x >> 6;
  if (lane == 0) { sh[0][wv] = v0; sh[1][wv] = v1; sh[2][wv] = v2; sh[3][wv] = v3; }
  __syncthreads();
  if (threadIdx.x == 0) {
    atomicAdd(&Stot[img * 2 + 0], sh[0][0] + sh[0][1] + sh[0][2] + sh[0][3]);
    atomicAdd(&Slt [img * 2 + 0], sh[1][0] + sh[1][1] + sh[1][2] + sh[1][3]);
    atomicAdd(&Stot[img * 2 + 1], sh[2][0] + sh[2][1] + sh[2][2] + sh[2][3]);
    atomicAdd(&Slt [img * 2 + 1], sh[3][0] + sh[3][1] + sh[3][2] + sh[3][3]);
  }
}

// ---------- exact median + MAD scale among candidates: one block per (img,arr) ----------
__global__ __launch_bounds__(256) void k_med(const float* __restrict__ cand,
    const u32* __restrict__ ccnt, const u32* __restrict__ cnt,
    const u32* __restrict__ selp, const u32* __restrict__ selr,
    const u32* __restrict__ nlt, const double* __restrict__ Stot,
    const double* __restrict__ Slt, float* __restrict__ med, float* __restrict__ sci)
{
  int t = blockIdx.x, img = t >> 1;
  u32 c = cnt[img];
  u32 n = ccnt[t]; if (n > CAP) n = CAP;
  const float* cd = cand + (size_t)t * CAP;
  u32 target = selr[t];
  __shared__ u32 h[2048];
  __shared__ u32 ps[256];
  __shared__ u32 sBin, sRank;
  __shared__ float sMed;
  if (threadIdx.x == 0) { sBin = 0; sRank = 0; sMed = 0.f; }
  for (int i = threadIdx.x; i < 2048; i += 256) h[i] = 0;
  __syncthreads();
  // pass A: bits [10..20] of key among candidates
  for (u32 j = threadIdx.x; j < n; j += 256) {
    u32 k = f2key(cd[j]);
    atomicAdd(&h[(k >> 10) & 0x7FFu], 1u);
  }
  __syncthreads();
  {
    int b0 = threadIdx.x * 8; u32 loc[8]; u32 s = 0;
    for (int j = 0; j < 8; j++) { loc[j] = h[b0 + j]; s += loc[j]; }
    ps[threadIdx.x] = s; __syncthreads();
    for (int off = 1; off < 256; off <<= 1) {
      u32 v = (threadIdx.x >= (u32)off) ? ps[threadIdx.x - off] : 0u;
      __syncthreads(); ps[threadIdx.x] += v; __syncthreads();
    }
    u32 cum = ps[threadIdx.x] - s;
    for (int j = 0; j < 8; j++) {
      u32 v = loc[j];
      if (c && target >= cum && target < cum + v) { sBin = (u32)(b0 + j); sRank = target - cum; }
      cum += v;
    }
  }
  __syncthreads();
  u32 binA = sBin, tgtB = sRank;
  for (int i = threadIdx.x; i < 1024; i += 256) h[i] = 0;
  __syncthreads();
  // pass B: low 10 bits within bin A
  for (u32 j = threadIdx.x; j < n; j += 256) {
    u32 k = f2key(cd[j]);
    if (((k >> 10) & 0x7FFu) == binA) atomicAdd(&h[k & 0x3FFu], 1u);
  }
  __syncthreads();
  {
    int b0 = threadIdx.x * 4; u32 loc[4]; u32 s = 0;
    for (int j = 0; j < 4; j++) { loc[j] = h[b0 + j]; s += loc[j]; }
    ps[threadIdx.x] = s; __syncthreads();
    for (int off = 1; off < 256; off <<= 1) {
      u32 v = (threadIdx.x >= (u32)off) ? ps[threadIdx.x - off] : 0u;
      __syncthreads(); ps[threadIdx.x] += v; __syncthreads();
    }
    u32 cum = ps[threadIdx.x] - s;
    for (int j = 0; j < 4; j++) {
      u32 v = loc[j];
      if (c && tgtB >= cum && tgtB < cum + v) {
        u32 key = (selp[t] << 21) | (binA << 10) | (u32)(b0 + j);
        sMed = key2f(key);
      }
      cum += v;
    }
  }
  __syncthreads();
  float m = sMed;
  // stats: strict-below-median count/sum within candidates
  u32 nlt2 = 0; float slt2 = 0.f;
  for (u32 j = threadIdx.x; j < n; j += 256) {
    float v = cd[j];
    if (v < m) { nlt2++; slt2 += v; }
  }
  double v0 = (double)nlt2, v1 = (double)slt2;
  for (int o = 32; o; o >>= 1) { v0 += __shfl_down(v0, o, 64); v1 += __shfl_down(v1, o, 64); }
  __shared__ double sh[2][4];
  int lane = threadIdx.x & 63, wv = threadIdx.x >> 6;
  if (lane == 0) { sh[0][wv] = v0; sh[1][wv] = v1; }
  __syncthreads();
  if (threadIdx.x == 0) {
    if (c) {
      double nl = (double)nlt[t] + sh[0][0] + sh[0][1] + sh[0][2] + sh[0][3];
      double sl = Slt[t] + sh[1][0] + sh[1][1] + sh[1][2] + sh[1][3];
      double md = (double)m;
      double mad = Stot[t] + 2.0 * md * nl - 2.0 * sl - md * (double)c;
      double sc = mad / (double)c + 1e-8;
      med[t] = m; sci[t] = (float)(1.0 / sc);
    } else { med[t] = 0.f; sci[t] = 1e8f; }
  }
}

// ---------- fused: D in registers + rho + scale-0 grad + pool0 (float2 loads) ----------
__global__ __launch_bounds__(320) void k_fuse0(const float* __restrict__ p,
    const float* __restrict__ y, const u8* __restrict__ mu,
    const float* __restrict__ medv, const float* __restrict__ sciv,
    float* __restrict__ P1, u8* __restrict__ M1,
    double* __restrict__ rho, double* __restrict__ gacc)
{
  int img = blockIdx.x / NB0, band = blockIdx.x % NB0;
  float mp = medv[img * 2 + 0], my = medv[img * 2 + 1];
  float ap = sciv[img * 2 + 0], ay = sciv[img * 2 + 1];
  const float* pb = p + (size_t)img * HW;
  const float* yb = y + (size_t)img * HW;
  const u8*   mb = mu + (size_t)img * HW;
  int ra = band * 16;
  int rb = min(ra + 16, H0);
  int rend = (rb < H0) ? rb + 1 : H0;
  int oc = threadIdx.x;
  bool act = oc < 259;
  int cc = act ? 2 * oc : 516;         // clamp idle lanes to a valid address (keeps shfl uniform)
  bool vn = act && (2 * oc + 2 < W0);
  int lane = threadIdx.x & 63;
  bool edge = (lane == 63);
  float gx = 0.f, gy = 0.f, rr = 0.f;
  int cx = 0, cy = 0;
  float pd0 = 0.f, pd1 = 0.f; u8 pm0 = 0, pm1 = 0;
  size_t rbase = (size_t)ra * W0;
  float2 pv = *(const float2*)(pb + rbase + cc);
  float2 yv = *(const float2*)(yb + rbase + cc);
  uchar2 mv = *(const uchar2*)(mb + rbase + cc);
  for (int r = ra; r < rend; ++r) {
    float2 pn2 = pv, yn2 = yv; uchar2 mn2 = mv;
    if (r + 1 < rend) {
      size_t nb2 = (size_t)(r + 1) * W0;
      pn2 = *(const float2*)(pb + nb2 + cc);
      yn2 = *(const float2*)(yb + nb2 + cc);
      mn2 = *(const uchar2*)(mb + nb2 + cc);
    }
    bool core = r < rb;
    float d0 = (pv.x - mp) * ap - (yv.x - my) * ay;
    float d1 = (pv.y - mp) * ap - (yv.y - my) * ay;
    u8 m0 = mv.x, m1 = mv.y;
    float dn = __shfl_down(d0, 1, 64);
    int mn = __shfl_down((int)m0, 1, 64);
    if (vn && edge) {                   // cross-wave boundary: direct loads
      size_t a = (size_t)r * W0 + (size_t)cc + 2;
      float pnb = pb[a], ynb = yb[a];
      dn = (pnb - mp) * ap - (ynb - my) * ay;
      mn = mb[a];
    }
    if (act) {
      if (core) {
        if (m0 & m1) { gx += fabsf(d1 - d0); cx++; }
        if (vn && m1 && mn) { gx += fabsf(dn - d1); cx++; }
        if (m0) rr += fabsf(d0);
        if (m1) rr += fabsf(d1);
      }
      if (r > ra) {
        if (m0 & pm0) { gy += fabsf(d0 - pd0); cy++; }
        if (m1 & pm1) { gy += fabsf(d1 - pd1); cy++; }
      }
      if (core && (r & 1)) {
        size_t o = (size_t)img * N1 + (size_t)(r >> 1) * 259 + oc;
        P1[o] = 0.25f * (pd0 + pd1 + d0 + d1);
        M1[o] = (u8)((pm0 | pm1 | m0 | m1) ? 1 : 0);
      }
    }
    pd0 = d0; pd1 = d1; pm0 = m0; pm1 = m1;
    pv = pn2; yv = yn2; mv = mn2;
  }
  double v0 = (double)gx, v1 = (double)cx, v2 = (double)gy, v3 = (double)cy, v4 = (double)rr;
  for (int o = 32; o; o >>= 1) {
    v0 += __shfl_down(v0, o, 64); v1 += __shfl_down(v1, o, 64);
    v2 += __shfl_down(v2, o, 64); v3 += __shfl_down(v3, o, 64);
    v4 += __shfl_down(v4, o, 64);
  }
  __shared__ double sh[5][5];
  int wv = threadIdx.x >> 6;
  if (lane == 0) { sh[0][wv] = v0; sh[1][wv] = v1; sh[2][wv] = v2; sh[3][wv] = v3; sh[4][wv] = v4; }
  __syncthreads();
  if (threadIdx.x == 0) {
    double a0 = 0, a1 = 0, a2 = 0, a3 = 0, a4 = 0;
    for (int w = 0; w < 5; w++) { a0 += sh[0][w]; a1 += sh[1][w]; a2 += sh[2][w]; a3 += sh[3][w]; a4 += sh[4][w]; }
    atomicAdd(&gacc[0], a0);
    atomicAdd(&gacc[1], a1);
    atomicAdd(&gacc[2], a2);
    atomicAdd(&gacc[3], a3);
    atomicAdd(&rho[img], a4);
  }
}

// ---------- generic grad+pool for scales 1,2 (Wout <= 256) ----------
__global__ __launch_bounds__(256) void k_gp(const float* __restrict__ Pin,
    const u8* __restrict__ Min, float* __restrict__ Pout, u8* __restrict__ Mout,
    int Win, int Hin, int Wout, int Hout, int nb, double* __restrict__ gaccS)
{
  int img = blockIdx.x / nb, band = blockIdx.x % nb;
  int npixI = Win * Hin, npixO = Wout * Hout;
  const float* pb = Pin + (size_t)img * npixI;
  const u8* mb = Min + (size_t)img * npixI;
  int poolEnd = 2 * Hout;
  int ra = band * 16;
  int rb = min(ra + 16, poolEnd);
  int rbx = (band == nb - 1) ? Hin : rb;
  int rend = (rbx < Hin) ? rbx + 1 : Hin;
  float gx = 0.f, gy = 0.f;
  int cx = 0, cy = 0;
  int oc = threadIdx.x;
  if (oc < Wout) {
    int c0 = 2 * oc, c1 = c0 + 1, cn = c0 + 2;
    bool vn = cn < Win;
    bool gyn = vn && (cn >= 2 * Wout);
    float pd0 = 0.f, pd1 = 0.f, pdn = 0.f;
    u8 pm0 = 0, pm1 = 0, pmn = 0;
    for (int r = ra; r < rend; ++r) {
      bool core = r < rbx;
      int base = r * Win;
      float d0 = pb[base + c0], d1 = pb[base + c1];
      u8 m0 = mb[base + c0], m1 = mb[base + c1];
      float dn = 0.f; u8 mn = 0;
      if (vn) { dn = pb[base + cn]; mn = mb[base + cn]; }
      if (core) {
        if (m0 & m1) { gx += fabsf(d1 - d0); cx++; }
        if (vn && (m1 & mn)) { gx += fabsf(dn - d1); cx++; }
      }
      if (r > ra) {
        if (m0 & pm0) { gy += fabsf(d0 - pd0); cy++; }
        if (m1 & pm1) { gy += fabsf(d1 - pd1); cy++; }
        if (gyn && (mn & pmn)) { gy += fabsf(dn - pdn); cy++; }
      }
      if (core && (r & 1) && r < poolEnd) {
        size_t o = (size_t)img * npixO + (size_t)(r >> 1) * Wout + oc;
        Pout[o] = 0.25f * (pd0 + pd1 + d0 + d1);
        Mout[o] = (u8)((pm0 | pm1 | m0 | m1) ? 1 : 0);
      }
      pd0 = d0; pd1 = d1; pdn = dn; pm0 = m0; pm1 = m1; pmn = mn;
    }
  }
  double v0 = (double)gx, v1 = (double)cx, v2 = (double)gy, v3 = (double)cy;
  for (int o = 32; o; o >>= 1) {
    v0 += __shfl_down(v0, o, 64); v1 += __shfl_down(v1, o, 64);
    v2 += __shfl_down(v2, o, 64); v3 += __shfl_down(v3, o, 64);
  }
  __shared__ double sh[4][4];
  int lane = threadIdx.x & 63, wv = threadIdx.x >> 6;
  if (lane == 0) { sh[0][wv] = v0; sh[1][wv] = v1; sh[2][wv] = v2; sh[3][wv] = v3; }
  __syncthreads();
  if (threadIdx.x == 0) {
    atomicAdd(&gaccS[0], sh[0][0] + sh[0][1] + sh[0][2] + sh[0][3]);
    atomicAdd(&gaccS[1], sh[1][0] + sh[1][1] + sh[1][2] + sh[1][3]);
    atomicAdd(&gaccS[2], sh[2][0] + sh[2][1] + sh[2][2] + sh[2][3]);
    atomicAdd(&gaccS[3], sh[3][0] + sh[3][1] + sh[3][2] + sh[3][3]);
  }
}

// ---------- scale-3 gradient (64x64) ----------
__global__ __launch_bounds__(256) void k_grad3(const float* __restrict__ P,
    const u8* __restrict__ M, double* __restrict__ gaccS)
{
  int t = blockIdx.x * 256 + threadIdx.x;
  int img = t >> 12, px = t & 4095;
  int col = px & 63;
  const float* Pi = P + ((size_t)img << 12);
  const u8* Mi = M + ((size_t)img << 12);
  float gx = 0.f, gy = 0.f;
  int cx = 0, cy = 0;
  float dc = Pi[px];
  u8 mc = Mi[px];
  if (col < 63 && mc && Mi[px + 1]) { gx = fabsf(Pi[px + 1] - dc); cx = 1; }
  if (px < 4032 && mc && Mi[px + 64]) { gy = fabsf(Pi[px + 64] - dc); cy = 1; }
  double v0 = (double)gx, v1 = (double)cx, v2 = (double)gy, v3 = (double)cy;
  for (int o = 32; o; o >>= 1) {
    v0 += __shfl_down(v0, o, 64); v1 += __shfl_down(v1, o, 64);
    v2 += __shfl_down(v2, o, 64); v3 += __shfl_down(v3, o, 64);
  }
  __shared__ double sh[4][4];
  int lane = threadIdx.x & 63, wv = threadIdx.x >> 6;
  if (lane == 0) { sh[0][wv] = v0; sh[1][wv] = v1; sh[2][wv] = v2; sh[3][wv] = v3; }
  __syncthreads();
  if (threadIdx.x == 0) {
    atomicAdd(&gaccS[0], sh[0][0] + sh[0][1] + sh[0][2] + sh[0][3]);
    atomicAdd(&gaccS[1], sh[1][0] + sh[1][1] + sh[1][2] + sh[1][3]);
    atomicAdd(&gaccS[2], sh[2][0] + sh[2][1] + sh[2][2] + sh[2][3]);
    atomicAdd(&gaccS[3], sh[3][0] + sh[3][1] + sh[3][2] + sh[3][3]);
  }
}

// ---------- finalize scalar ----------
__global__ void k_final(const double* __restrict__ rho, const u32* __restrict__ cnt,
                        const double* __restrict__ gacc, float* __restrict__ out)
{
  if (threadIdx.x == 0 && blockIdx.x == 0) {
    double ssi = 0.0;
    for (int i = 0; i < NIMG; i++) {
      double c = cnt[i] ? (double)cnt[i] : 1.0;
      ssi += rho[i] / c;
    }
    ssi /= (double)NIMG;
    double g = 0.0;
    for (int s = 0; s < 4; s++) {
      double cx = gacc[s * 4 + 1], cy = gacc[s * 4 + 3];
      g += gacc[s * 4 + 0] / (cx > 1.0 ? cx : 1.0);
      g += gacc[s * 4 + 2] / (cy > 1.0 ? cy : 1.0);
    }
    g /= 4.0;
    out[0] = (float)(ssi + 0.5 * g);
  }
}

extern "C" void kernel_launch(void* const* d_in, const int* in_sizes, int n_in,
                              void* d_out, int out_size, void* d_ws, size_t ws_size,
                              hipStream_t stream) {
  (void)in_sizes; (void)n_in; (void)out_size; (void)ws_size;
  const float4* p4 = (const float4*)d_in[0];
  const float4* y4 = (const float4*)d_in[1];
  const int4* m4 = (const int4*)d_in[2];
  const float* pf = (const float*)d_in[0];
  const float* yf = (const float*)d_in[1];
  u8* ws = (u8*)d_ws;

  u32*    Hg   = (u32*)(ws + OFF_HG);
  u32*    cnt  = (u32*)(ws + OFF_CNT);
  u32*    selp = (u32*)(ws + OFF_SELP);
  u32*    selr = (u32*)(ws + OFF_SELR);
  u32*    nlt  = (u32*)(ws + OFF_NLT);
  double* Stot = (double*)(ws + OFF_STOT);
  double* Slt  = (double*)(ws + OFF_SLT);
  float*  med  = (float*)(ws + OFF_MED);
  float*  sci  = (float*)(ws + OFF_SCI);
  double* rho  = (double*)(ws + OFF_RHO);
  double* gacc = (double*)(ws + OFF_GACC);
  u32*    ccnt = (u32*)(ws + OFF_CCNT);
  float*  cand = (float*)(ws + OFF_CAND);
  u8*     mu8  = (u8*)(ws + OFF_MU8);
  float*  P1   = (float*)(ws + OFF_P1);
  u8*     M1   = (u8*)(ws + OFF_M1);
  float*  P2   = (float*)(ws + OFF_P2);
  u8*     M2   = (u8*)(ws + OFF_M2);
  float*  P3   = (float*)(ws + OFF_P3);
  u8*     M3   = (u8*)(ws + OFF_M3);

  hipMemsetAsync(d_ws, 0, SMALL_END, stream);

  k_hist0<<<NIMG * BPI, 256, 0, stream>>>(p4, y4, m4, (uchar4*)mu8, Hg, cnt);
  k_sel0<<<128, 256, 0, stream>>>(Hg, cnt, selp, selr, nlt);
  k_compact<<<NIMG * BPI, 256, 0, stream>>>(p4, y4, (const uchar4*)mu8, selp, cand, ccnt, Stot, Slt);
  k_med<<<128, 256, 0, stream>>>(cand, ccnt, cnt, selp, selr, nlt, Stot, Slt, med, sci);

  k_fuse0<<<NIMG * NB0, 320, 0, stream>>>(pf, yf, mu8, med, sci, P1, M1, rho, gacc);
  k_gp<<<NIMG * 17, 256, 0, stream>>>(P1, M1, P2, M2, 259, 259, 129, 129, 17, gacc + 4);
  k_gp<<<NIMG * 8, 256, 0, stream>>>(P2, M2, P3, M3, 129, 129, 64, 64, 8, gacc + 8);
  k_grad3<<<1024, 256, 0, stream>>>(P3, M3, gacc + 12);

  k_final<<<1, 64, 0, stream>>>(rho, cnt, gacc, (float*)d_out);
}

// Round 5
// 402.617 us; speedup vs baseline: 1.6712x; 1.2982x over previous
//
#include <hip/hip_runtime.h>
#include <stdint.h>

typedef unsigned int u32;
typedef unsigned char u8;

#define NIMG 64
#define W0   518
#define H0   518
#define HW   268324
#define HW4  67081
#define BPI  32
#define NB0  33
#define N1 67081
#define N2 16641
#define N3 4096
#define CAP 32768
#define LCAP 1536

// ---- workspace byte offsets ----
#define OFF_HFB   0ULL           // u32[128][2048] fallback hist
#define OFF_CNT   1048576ULL     // u32[64]
#define OFF_CCNT  1048832ULL     // u32[128]
#define OFF_CCNT2 1049344ULL     // u32[128]
#define OFF_NBL   1049856ULL     // u32[128]
#define OFF_OK    1050368ULL     // u32[128]
#define OFF_SELP  1050880ULL     // u32[128]
#define OFF_SELR  1051392ULL     // u32[128]
#define OFF_NLT   1051904ULL     // u32[128]
#define OFF_STOT  1052416ULL     // double[128]
#define OFF_SBL   1053440ULL     // double[128]
#define OFF_SLTFB 1054464ULL     // double[128]
#define OFF_RHO   1055488ULL     // double[64]
#define OFF_GI0   1056000ULL     // double[64*4]
#define OFF_GI1   1058048ULL
#define OFF_GI2   1060096ULL
#define OFF_GI3   1062144ULL
#define SMALL_END 1064192ULL
#define OFF_MED   1064192ULL     // float[128]
#define OFF_SCI   1064704ULL     // float[128]
#define OFF_SELW  1065216ULL     // u32[256]
#define OFF_CAND  1067008ULL                   // float[128][CAP] = 16 MB
#define OFF_MU8   (OFF_CAND + 16777216ULL)     // u8[64*268324]
#define OFF_P1    (OFF_MU8 + 17172736ULL)
#define OFF_M1    (OFF_P1 + 17172736ULL)
#define OFF_P2    (OFF_M1 + 4293184ULL)
#define OFF_M2    (OFF_P2 + 4260096ULL)
#define OFF_P3    (OFF_M2 + 1065024ULL)
#define OFF_M3    (OFF_P3 + 1048576ULL)

__device__ __forceinline__ u32 f2key(float f) {
  u32 u = __float_as_uint(f);
  return (u & 0x80000000u) ? ~u : (u | 0x80000000u);
}
__device__ __forceinline__ float key2f(u32 k) {
  u32 u = (k & 0x80000000u) ? (k & 0x7fffffffu) : ~k;
  return __uint_as_float(u);
}

// block-wide rank-find over LDS hist h[per*256]; writes *outBin/*outRank (shared) at the found bin.
__device__ void blk_rankfind(u32* h, u32* ps, int per, u32 target, bool enable,
                             u32* outBin, u32* outRank)
{
  int b0 = threadIdx.x * per;
  u32 s = 0;
  for (int j = 0; j < per; j++) s += h[b0 + j];
  ps[threadIdx.x] = s;
  __syncthreads();
  for (int off = 1; off < 256; off <<= 1) {
    u32 v = (threadIdx.x >= (u32)off) ? ps[threadIdx.x - off] : 0u;
    __syncthreads();
    ps[threadIdx.x] += v;
    __syncthreads();
  }
  u32 cum = ps[threadIdx.x] - s;
  for (int j = 0; j < per; j++) {
    u32 v = h[b0 + j];
    if (enable && target >= cum && target < cum + v) { *outBin = (u32)(b0 + j); *outRank = target - cum; }
    cum += v;
  }
  __syncthreads();
}

// ---------- sample: approximate median window in key space ----------
__global__ __launch_bounds__(256) void k_sample(const float* __restrict__ p,
    const float* __restrict__ y, u32* __restrict__ selw)
{
  int t = blockIdx.x, img = t >> 1;
  const float* src = ((t & 1) ? y : p) + (size_t)img * HW;
  __shared__ u32 h[2048];
  __shared__ u32 ps[256];
  __shared__ u32 bLo, rLo, bHi, rHi;
  if (threadIdx.x == 0) { bLo = 0; rLo = 0; bHi = 2047; rHi = 0; }
  for (int i = threadIdx.x; i < 2048; i += 256) h[i] = 0;
  __syncthreads();
  for (int j = 0; j < 16; j++) {
    int s = threadIdx.x * 16 + j;
    float v = src[s * 65 + 32];
    atomicAdd(&h[f2key(v) >> 21], 1u);
  }
  __syncthreads();
  blk_rankfind(h, ps, 8, 1855u, true, &bLo, &rLo);
  blk_rankfind(h, ps, 8, 2239u, true, &bHi, &rHi);
  if (threadIdx.x == 0) {
    u32 k0 = bLo << 21;
    u32 k1 = (bHi >= 2047u) ? 0xFFFFFFFFu : ((bHi + 1u) << 21);
    selw[2 * t + 0] = k0;
    selw[2 * t + 1] = k1;
  }
}

// ---------- single full scan: mask write, cnt, Stot, below-window stats, window capture ----------
__global__ __launch_bounds__(256) void k_scan0(const float4* __restrict__ p,
    const float4* __restrict__ y, const int4* __restrict__ m,
    uchar4* __restrict__ mu4, const u32* __restrict__ selw,
    float* __restrict__ cand, u32* __restrict__ ccnt, u32* __restrict__ cnt,
    double* __restrict__ Stot, u32* __restrict__ Nbl, double* __restrict__ Sbl)
{
  __shared__ float capP[LCAP], capY[LCAP];
  __shared__ u32 nP, nY, baseP, baseY;
  if (threadIdx.x == 0) { nP = 0; nY = 0; }
  __syncthreads();
  int img = blockIdx.x / BPI, blk = blockIdx.x % BPI;
  u32 k0P = selw[img * 4 + 0], k1P = selw[img * 4 + 1];
  u32 k0Y = selw[img * 4 + 2], k1Y = selw[img * 4 + 3];
  const float4* pb = p + (size_t)img * HW4;
  const float4* yb = y + (size_t)img * HW4;
  const int4* mb = m + (size_t)img * HW4;
  uchar4* mo = mu4 + (size_t)img * HW4;
  int lc = 0, nB_p = 0, nB_y = 0;
  float sT_p = 0.f, sB_p = 0.f, sT_y = 0.f, sB_y = 0.f;
  for (int i = blk * 256 + threadIdx.x; i < HW4; i += BPI * 256) {
    float4 pv = pb[i], yv = yb[i];
    int4 mv = mb[i];
    uchar4 mw;
    mw.x = mv.x ? 1 : 0; mw.y = mv.y ? 1 : 0; mw.z = mv.z ? 1 : 0; mw.w = mv.w ? 1 : 0;
    mo[i] = mw;
#define SC(mm, vp, vy) if (mm) { lc++; \
      float v = vp; u32 k = f2key(v); sT_p += v; \
      if (k < k0P) { nB_p++; sB_p += v; } \
      else if (k < k1P) { u32 ix = atomicAdd(&nP, 1u); if (ix < LCAP) capP[ix] = v; } \
      v = vy; k = f2key(v); sT_y += v; \
      if (k < k0Y) { nB_y++; sB_y += v; } \
      else if (k < k1Y) { u32 ix = atomicAdd(&nY, 1u); if (ix < LCAP) capY[ix] = v; } }
    SC(mw.x, pv.x, yv.x) SC(mw.y, pv.y, yv.y) SC(mw.z, pv.z, yv.z) SC(mw.w, pv.w, yv.w)
#undef SC
  }
  __syncthreads();
  if (threadIdx.x == 0) {
    u32 np = nP, ny = nY;
    u32 addP = (np > (u32)LCAP) ? (u32)(CAP + 1) : np;
    u32 addY = (ny > (u32)LCAP) ? (u32)(CAP + 1) : ny;
    baseP = atomicAdd(&ccnt[img * 2 + 0], addP);
    baseY = atomicAdd(&ccnt[img * 2 + 1], addY);
  }
  __syncthreads();
  {
    u32 np = min(nP, (u32)LCAP), ny = min(nY, (u32)LCAP);
    float* cp = cand + (size_t)(img * 2 + 0) * CAP;
    float* cy = cand + (size_t)(img * 2 + 1) * CAP;
    for (u32 i = threadIdx.x; i < np; i += 256) { u32 g = baseP + i; if (g < CAP) cp[g] = capP[i]; }
    for (u32 i = threadIdx.x; i < ny; i += 256) { u32 g = baseY + i; if (g < CAP) cy[g] = capY[i]; }
  }
  double v0 = (double)sT_p, v1 = (double)sB_p, v2 = (double)sT_y, v3 = (double)sB_y;
  double v4 = (double)lc, v5 = (double)nB_p, v6 = (double)nB_y;
  for (int o = 32; o; o >>= 1) {
    v0 += __shfl_down(v0, o, 64); v1 += __shfl_down(v1, o, 64);
    v2 += __shfl_down(v2, o, 64); v3 += __shfl_down(v3, o, 64);
    v4 += __shfl_down(v4, o, 64); v5 += __shfl_down(v5, o, 64);
    v6 += __shfl_down(v6, o, 64);
  }
  __shared__ double sh[7][4];
  int lane = threadIdx.x & 63, wv = threadIdx.x >> 6;
  if (lane == 0) { sh[0][wv]=v0; sh[1][wv]=v1; sh[2][wv]=v2; sh[3][wv]=v3; sh[4][wv]=v4; sh[5][wv]=v5; sh[6][wv]=v6; }
  __syncthreads();
  if (threadIdx.x == 0) {
    double a[7];
    for (int k = 0; k < 7; k++) a[k] = sh[k][0] + sh[k][1] + sh[k][2] + sh[k][3];
    atomicAdd(&Stot[img * 2 + 0], a[0]);
    atomicAdd(&Sbl [img * 2 + 0], a[1]);
    atomicAdd(&Stot[img * 2 + 1], a[2]);
    atomicAdd(&Sbl [img * 2 + 1], a[3]);
    atomicAdd(&cnt[img], (u32)a[4]);
    atomicAdd(&Nbl[img * 2 + 0], (u32)a[5]);
    atomicAdd(&Nbl[img * 2 + 1], (u32)a[6]);
  }
}

// ---------- exact median + MAD among captured window (fast path) ----------
__global__ __launch_bounds__(256) void k_med2(const float* __restrict__ cand,
    const u32* __restrict__ ccnt, const u32* __restrict__ cnt,
    const u32* __restrict__ Nbl, const double* __restrict__ Stot,
    const double* __restrict__ Sbl, float* __restrict__ med,
    float* __restrict__ sci, u32* __restrict__ ok)
{
  int t = blockIdx.x, img = t >> 1;
  u32 c = cnt[img];
  if (c == 0) {
    if (threadIdx.x == 0) { med[t] = 0.f; sci[t] = 1e8f; ok[t] = 1; }
    return;
  }
  u32 ntot = ccnt[t];
  u32 target0 = (c - 1) >> 1;
  u32 nb = Nbl[t];
  bool valid = (ntot <= (u32)CAP) && (target0 >= nb) && ((target0 - nb) < ntot);
  if (!valid) { if (threadIdx.x == 0) ok[t] = 0; return; }
  u32 n = ntot;
  u32 target = target0 - nb;
  const float* cd = cand + (size_t)t * CAP;
  __shared__ u32 h[2048];
  __shared__ u32 ps[256];
  __shared__ u32 sBin, sRank;
  if (threadIdx.x == 0) { sBin = 0; sRank = 0; }
  // pass 1: key bits [31:21]
  for (int i = threadIdx.x; i < 2048; i += 256) h[i] = 0;
  __syncthreads();
  for (u32 j = threadIdx.x; j < n; j += 256) atomicAdd(&h[f2key(cd[j]) >> 21], 1u);
  __syncthreads();
  blk_rankfind(h, ps, 8, target, true, &sBin, &sRank);
  u32 bin1 = sBin, t1 = sRank;
  // pass 2: bits [20:10] within bin1
  for (int i = threadIdx.x; i < 2048; i += 256) h[i] = 0;
  __syncthreads();
  for (u32 j = threadIdx.x; j < n; j += 256) {
    u32 k = f2key(cd[j]);
    if ((k >> 21) == bin1) atomicAdd(&h[(k >> 10) & 0x7FFu], 1u);
  }
  __syncthreads();
  blk_rankfind(h, ps, 8, t1, true, &sBin, &sRank);
  u32 bin2 = sBin, t2 = sRank;
  // pass 3: bits [9:0] within (bin1,bin2)
  u32 pref = (bin1 << 11) | bin2;
  for (int i = threadIdx.x; i < 1024; i += 256) h[i] = 0;
  __syncthreads();
  for (u32 j = threadIdx.x; j < n; j += 256) {
    u32 k = f2key(cd[j]);
    if ((k >> 10) == pref) atomicAdd(&h[k & 0x3FFu], 1u);
  }
  __syncthreads();
  blk_rankfind(h, ps, 4, t2, true, &sBin, &sRank);
  float m = key2f((pref << 10) | sBin);
  // corrections among captured: count/sum of v < m
  u32 nlt2 = 0; float slt2 = 0.f;
  for (u32 j = threadIdx.x; j < n; j += 256) {
    float v = cd[j];
    if (v < m) { nlt2++; slt2 += v; }
  }
  double v0 = (double)nlt2, v1 = (double)slt2;
  for (int o = 32; o; o >>= 1) { v0 += __shfl_down(v0, o, 64); v1 += __shfl_down(v1, o, 64); }
  __shared__ double sh2[2][4];
  int lane = threadIdx.x & 63, wv = threadIdx.x >> 6;
  if (lane == 0) { sh2[0][wv] = v0; sh2[1][wv] = v1; }
  __syncthreads();
  if (threadIdx.x == 0) {
    double nl = (double)nb + sh2[0][0] + sh2[0][1] + sh2[0][2] + sh2[0][3];
    double sl = Sbl[t] + sh2[1][0] + sh2[1][1] + sh2[1][2] + sh2[1][3];
    double md = (double)m;
    double mad = Stot[t] + 2.0 * md * nl - 2.0 * sl - md * (double)c;
    double sc = mad / (double)c + 1e-8;
    med[t] = m; sci[t] = (float)(1.0 / sc); ok[t] = 1;
  }
}

// ---------- fallback chain (early-exit when fast path succeeded) ----------
__global__ __launch_bounds__(256) void k_fb_hist(const float4* __restrict__ p,
    const float4* __restrict__ y, const uchar4* __restrict__ mu,
    const u32* __restrict__ ok, u32* __restrict__ hist)
{
  int img = blockIdx.x / BPI, blk = blockIdx.x % BPI;
  if (ok[img * 2 + 0] && ok[img * 2 + 1]) return;
  __shared__ u32 h[4096];
  for (int i = threadIdx.x; i < 4096; i += 256) h[i] = 0;
  __syncthreads();
  const float4* pb = p + (size_t)img * HW4;
  const float4* yb = y + (size_t)img * HW4;
  const uchar4* mb = mu + (size_t)img * HW4;
  for (int i = blk * 256 + threadIdx.x; i < HW4; i += BPI * 256) {
    float4 pv = pb[i], yv = yb[i];
    uchar4 mv = mb[i];
#define FH(mm, vp, vy) if (mm) { atomicAdd(&h[f2key(vp) >> 21], 1u); atomicAdd(&h[2048u + (f2key(vy) >> 21)], 1u); }
    FH(mv.x, pv.x, yv.x) FH(mv.y, pv.y, yv.y) FH(mv.z, pv.z, yv.z) FH(mv.w, pv.w, yv.w)
#undef FH
  }
  __syncthreads();
  u32* gh = hist + (size_t)img * 4096;
  for (int b = threadIdx.x; b < 4096; b += 256) if (h[b]) atomicAdd(&gh[b], h[b]);
}

__global__ __launch_bounds__(256) void k_fb_sel(const u32* __restrict__ hist,
    const u32* __restrict__ cnt, const u32* __restrict__ ok,
    u32* __restrict__ selp, u32* __restrict__ selr, u32* __restrict__ nlt)
{
  int t = blockIdx.x, img = t >> 1;
  if (ok[t]) return;
  __shared__ u32 hh[2048];
  __shared__ u32 ps[256];
  __shared__ u32 sBin, sRank;
  if (threadIdx.x == 0) { sBin = 0; sRank = 0; }
  const u32* gh = hist + (size_t)t * 2048;
  for (int i = threadIdx.x; i < 2048; i += 256) hh[i] = gh[i];
  __syncthreads();
  u32 c = cnt[img];
  u32 target = c ? ((c - 1) >> 1) : 0u;
  blk_rankfind(hh, ps, 8, target, c != 0, &sBin, &sRank);
  if (threadIdx.x == 0) { selp[t] = sBin; selr[t] = sRank; nlt[t] = target - sRank; }
}

__global__ __launch_bounds__(256) void k_fb_compact(const float4* __restrict__ p,
    const float4* __restrict__ y, const uchar4* __restrict__ mu,
    const u32* __restrict__ ok, const u32* __restrict__ selp,
    float* __restrict__ cand, u32* __restrict__ ccnt2, double* __restrict__ Sltfb)
{
  int img = blockIdx.x / BPI, blk = blockIdx.x % BPI;
  if (ok[img * 2 + 0] && ok[img * 2 + 1]) return;
  u32 binP = selp[img * 2 + 0], binY = selp[img * 2 + 1];
  const float4* pb = p + (size_t)img * HW4;
  const float4* yb = y + (size_t)img * HW4;
  const uchar4* mb = mu + (size_t)img * HW4;
  float* cp = cand + (size_t)(img * 2 + 0) * CAP;
  float* cyv = cand + (size_t)(img * 2 + 1) * CAP;
  u32* ccP = &ccnt2[img * 2 + 0];
  u32* ccY = &ccnt2[img * 2 + 1];
  float sLp = 0.f, sLy = 0.f;
  for (int i = blk * 256 + threadIdx.x; i < HW4; i += BPI * 256) {
    float4 pv = pb[i], yv = yb[i];
    uchar4 mv = mb[i];
#define FC(mm, vp, vy) if (mm) { \
      float v = vp; u32 b = f2key(v) >> 21; \
      if (b < binP) sLp += v; else if (b == binP) { u32 ix = atomicAdd(ccP, 1u); if (ix < CAP) cp[ix] = v; } \
      v = vy; b = f2key(v) >> 21; \
      if (b < binY) sLy += v; else if (b == binY) { u32 ix = atomicAdd(ccY, 1u); if (ix < CAP) cyv[ix] = v; } }
    FC(mv.x, pv.x, yv.x) FC(mv.y, pv.y, yv.y) FC(mv.z, pv.z, yv.z) FC(mv.w, pv.w, yv.w)
#undef FC
  }
  double v0 = (double)sLp, v1 = (double)sLy;
  for (int o = 32; o; o >>= 1) { v0 += __shfl_down(v0, o, 64); v1 += __shfl_down(v1, o, 64); }
  __shared__ double sh[2][4];
  int lane = threadIdx.x & 63, wv = threadIdx.x >> 6;
  if (lane == 0) { sh[0][wv] = v0; sh[1][wv] = v1; }
  __syncthreads();
  if (threadIdx.x == 0) {
    atomicAdd(&Sltfb[img * 2 + 0], sh[0][0] + sh[0][1] + sh[0][2] + sh[0][3]);
    atomicAdd(&Sltfb[img * 2 + 1], sh[1][0] + sh[1][1] + sh[1][2] + sh[1][3]);
  }
}

__global__ __launch_bounds__(256) void k_fb_med(const float* __restrict__ cand,
    const u32* __restrict__ ccnt2, const u32* __restrict__ cnt,
    const u32* __restrict__ ok, const u32* __restrict__ selp,
    const u32* __restrict__ selr, const u32* __restrict__ nlt,
    const double* __restrict__ Stot, const double* __restrict__ Sltfb,
    float* __restrict__ med, float* __restrict__ sci)
{
  int t = blockIdx.x, img = t >> 1;
  if (ok[t]) return;
  u32 c = cnt[img];
  u32 n = ccnt2[t]; if (n > CAP) n = CAP;
  const float* cd = cand + (size_t)t * CAP;
  u32 target = selr[t];
  __shared__ u32 h[2048];
  __shared__ u32 ps[256];
  __shared__ u32 sBin, sRank;
  if (threadIdx.x == 0) { sBin = 0; sRank = 0; }
  for (int i = threadIdx.x; i < 2048; i += 256) h[i] = 0;
  __syncthreads();
  for (u32 j = threadIdx.x; j < n; j += 256) {
    u32 k = f2key(cd[j]);
    atomicAdd(&h[(k >> 10) & 0x7FFu], 1u);
  }
  __syncthreads();
  blk_rankfind(h, ps, 8, target, c != 0, &sBin, &sRank);
  u32 binA = sBin, tgtB = sRank;
  for (int i = threadIdx.x; i < 1024; i += 256) h[i] = 0;
  __syncthreads();
  for (u32 j = threadIdx.x; j < n; j += 256) {
    u32 k = f2key(cd[j]);
    if (((k >> 10) & 0x7FFu) == binA) atomicAdd(&h[k & 0x3FFu], 1u);
  }
  __syncthreads();
  blk_rankfind(h, ps, 4, tgtB, c != 0, &sBin, &sRank);
  float m = key2f((selp[t] << 21) | (binA << 10) | sBin);
  u32 nlt2 = 0; float slt2 = 0.f;
  for (u32 j = threadIdx.x; j < n; j += 256) {
    float v = cd[j];
    if (v < m) { nlt2++; slt2 += v; }
  }
  double v0 = (double)nlt2, v1 = (double)slt2;
  for (int o = 32; o; o >>= 1) { v0 += __shfl_down(v0, o, 64); v1 += __shfl_down(v1, o, 64); }
  __shared__ double sh2[2][4];
  int lane = threadIdx.x & 63, wv = threadIdx.x >> 6;
  if (lane == 0) { sh2[0][wv] = v0; sh2[1][wv] = v1; }
  __syncthreads();
  if (threadIdx.x == 0) {
    if (c) {
      double nl = (double)nlt[t] + sh2[0][0] + sh2[0][1] + sh2[0][2] + sh2[0][3];
      double sl = Sltfb[t] + sh2[1][0] + sh2[1][1] + sh2[1][2] + sh2[1][3];
      double md = (double)m;
      double mad = Stot[t] + 2.0 * md * nl - 2.0 * sl - md * (double)c;
      double sc = mad / (double)c + 1e-8;
      med[t] = m; sci[t] = (float)(1.0 / sc);
    } else { med[t] = 0.f; sci[t] = 1e8f; }
  }
}

// ---------- fused: D in registers + rho + scale-0 grad + pool0 ----------
__global__ __launch_bounds__(320) void k_fuse0(const float* __restrict__ p,
    const float* __restrict__ y, const u8* __restrict__ mu,
    const float* __restrict__ medv, const float* __restrict__ sciv,
    float* __restrict__ P1, u8* __restrict__ M1,
    double* __restrict__ rho, double* __restrict__ gI)
{
  int img = blockIdx.x / NB0, band = blockIdx.x % NB0;
  float mp = medv[img * 2 + 0], my = medv[img * 2 + 1];
  float ap = sciv[img * 2 + 0], ay = sciv[img * 2 + 1];
  const float* pb = p + (size_t)img * HW;
  const float* yb = y + (size_t)img * HW;
  const u8*   mb = mu + (size_t)img * HW;
  int ra = band * 16;
  int rb = min(ra + 16, H0);
  int rend = (rb < H0) ? rb + 1 : H0;
  int oc = threadIdx.x;
  bool act = oc < 259;
  int cc = act ? 2 * oc : 516;
  bool vn = act && (2 * oc + 2 < W0);
  int lane = threadIdx.x & 63;
  bool edge = (lane == 63);
  float gx = 0.f, gy = 0.f, rr = 0.f;
  int cx = 0, cy = 0;
  float pd0 = 0.f, pd1 = 0.f; u8 pm0 = 0, pm1 = 0;
  size_t rbase = (size_t)ra * W0;
  float2 pv = *(const float2*)(pb + rbase + cc);
  float2 yv = *(const float2*)(yb + rbase + cc);
  uchar2 mv = *(const uchar2*)(mb + rbase + cc);
  for (int r = ra; r < rend; ++r) {
    float2 pn2 = pv, yn2 = yv; uchar2 mn2 = mv;
    if (r + 1 < rend) {
      size_t nb2 = (size_t)(r + 1) * W0;
      pn2 = *(const float2*)(pb + nb2 + cc);
      yn2 = *(const float2*)(yb + nb2 + cc);
      mn2 = *(const uchar2*)(mb + nb2 + cc);
    }
    bool core = r < rb;
    float d0 = (pv.x - mp) * ap - (yv.x - my) * ay;
    float d1 = (pv.y - mp) * ap - (yv.y - my) * ay;
    u8 m0 = mv.x, m1 = mv.y;
    float dn = __shfl_down(d0, 1, 64);
    int mn = __shfl_down((int)m0, 1, 64);
    if (vn && edge) {
      size_t a = (size_t)r * W0 + (size_t)cc + 2;
      float pnb = pb[a], ynb = yb[a];
      dn = (pnb - mp) * ap - (ynb - my) * ay;
      mn = mb[a];
    }
    if (act) {
      float f0 = (float)m0, f1 = (float)m1;
      if (core) {
        gx += f0 * f1 * fabsf(d1 - d0); cx += (int)(m0 & m1);
        if (vn) { float fn = (float)mn; gx += f1 * fn * fabsf(dn - d1); cx += (m1 && mn) ? 1 : 0; }
        rr += f0 * fabsf(d0) + f1 * fabsf(d1);
      }
      if (r > ra) {
        gy += f0 * (float)pm0 * fabsf(d0 - pd0); cy += (int)(m0 & pm0);
        gy += f1 * (float)pm1 * fabsf(d1 - pd1); cy += (int)(m1 & pm1);
      }
      if (core && (r & 1)) {
        size_t o = (size_t)img * N1 + (size_t)(r >> 1) * 259 + oc;
        P1[o] = 0.25f * (pd0 + pd1 + d0 + d1);
        M1[o] = (u8)((pm0 | pm1 | m0 | m1) ? 1 : 0);
      }
    }
    pd0 = d0; pd1 = d1; pm0 = m0; pm1 = m1;
    pv = pn2; yv = yn2; mv = mn2;
  }
  double v0 = (double)gx, v1 = (double)cx, v2 = (double)gy, v3 = (double)cy, v4 = (double)rr;
  for (int o = 32; o; o >>= 1) {
    v0 += __shfl_down(v0, o, 64); v1 += __shfl_down(v1, o, 64);
    v2 += __shfl_down(v2, o, 64); v3 += __shfl_down(v3, o, 64);
    v4 += __shfl_down(v4, o, 64);
  }
  __shared__ double sh[5][5];
  int wv = threadIdx.x >> 6;
  if (lane == 0) { sh[0][wv] = v0; sh[1][wv] = v1; sh[2][wv] = v2; sh[3][wv] = v3; sh[4][wv] = v4; }
  __syncthreads();
  if (threadIdx.x == 0) {
    double a0 = 0, a1 = 0, a2 = 0, a3 = 0, a4 = 0;
    for (int w = 0; w < 5; w++) { a0 += sh[0][w]; a1 += sh[1][w]; a2 += sh[2][w]; a3 += sh[3][w]; a4 += sh[4][w]; }
    atomicAdd(&gI[img * 4 + 0], a0);
    atomicAdd(&gI[img * 4 + 1], a1);
    atomicAdd(&gI[img * 4 + 2], a2);
    atomicAdd(&gI[img * 4 + 3], a3);
    atomicAdd(&rho[img], a4);
  }
}

// ---------- generic grad+pool (per-image accumulators) ----------
__global__ void k_gp(const float* __restrict__ Pin,
    const u8* __restrict__ Min, float* __restrict__ Pout, u8* __restrict__ Mout,
    int Win, int Hin, int Wout, int Hout, int nb, double* __restrict__ gI)
{
  int img = blockIdx.x / nb, band = blockIdx.x % nb;
  int npixI = Win * Hin, npixO = Wout * Hout;
  const float* pb = Pin + (size_t)img * npixI;
  const u8* mb = Min + (size_t)img * npixI;
  int poolEnd = 2 * Hout;
  int ra = band * 16;
  int rb = min(ra + 16, poolEnd);
  int rbx = (band == nb - 1) ? Hin : rb;
  int rend = (rbx < Hin) ? rbx + 1 : Hin;
  float gx = 0.f, gy = 0.f;
  int cx = 0, cy = 0;
  int oc = threadIdx.x;
  if (oc < Wout) {
    int c0 = 2 * oc, c1 = c0 + 1, cn = c0 + 2;
    bool vn = cn < Win;
    bool gyn = vn && (cn >= 2 * Wout);
    float pd0 = 0.f, pd1 = 0.f, pdn = 0.f;
    u8 pm0 = 0, pm1 = 0, pmn = 0;
    for (int r = ra; r < rend; ++r) {
      bool core = r < rbx;
      int base = r * Win;
      float d0 = pb[base + c0], d1 = pb[base + c1];
      u8 m0 = mb[base + c0], m1 = mb[base + c1];
      float dn = 0.f; u8 mn = 0;
      if (vn) { dn = pb[base + cn]; mn = mb[base + cn]; }
      if (core) {
        if (m0 & m1) { gx += fabsf(d1 - d0); cx++; }
        if (vn && (m1 & mn)) { gx += fabsf(dn - d1); cx++; }
      }
      if (r > ra) {
        if (m0 & pm0) { gy += fabsf(d0 - pd0); cy++; }
        if (m1 & pm1) { gy += fabsf(d1 - pd1); cy++; }
        if (gyn && (mn & pmn)) { gy += fabsf(dn - pdn); cy++; }
      }
      if (core && (r & 1) && r < poolEnd) {
        size_t o = (size_t)img * npixO + (size_t)(r >> 1) * Wout + oc;
        Pout[o] = 0.25f * (pd0 + pd1 + d0 + d1);
        Mout[o] = (u8)((pm0 | pm1 | m0 | m1) ? 1 : 0);
      }
      pd0 = d0; pd1 = d1; pdn = dn; pm0 = m0; pm1 = m1; pmn = mn;
    }
  }
  double v0 = (double)gx, v1 = (double)cx, v2 = (double)gy, v3 = (double)cy;
  for (int o = 32; o; o >>= 1) {
    v0 += __shfl_down(v0, o, 64); v1 += __shfl_down(v1, o, 64);
    v2 += __shfl_down(v2, o, 64); v3 += __shfl_down(v3, o, 64);
  }
  __shared__ double sh[4][4];
  int lane = threadIdx.x & 63, wv = threadIdx.x >> 6;
  int nw = (blockDim.x + 63) >> 6;
  if (lane == 0) { sh[0][wv] = v0; sh[1][wv] = v1; sh[2][wv] = v2; sh[3][wv] = v3; }
  __syncthreads();
  if (threadIdx.x == 0) {
    double a0 = 0, a1 = 0, a2 = 0, a3 = 0;
    for (int w = 0; w < nw; w++) { a0 += sh[0][w]; a1 += sh[1][w]; a2 += sh[2][w]; a3 += sh[3][w]; }
    atomicAdd(&gI[img * 4 + 0], a0);
    atomicAdd(&gI[img * 4 + 1], a1);
    atomicAdd(&gI[img * 4 + 2], a2);
    atomicAdd(&gI[img * 4 + 3], a3);
  }
}

// ---------- scale-3 gradient ----------
__global__ __launch_bounds__(256) void k_grad3(const float* __restrict__ P,
    const u8* __restrict__ M, double* __restrict__ gI)
{
  int t = blockIdx.x * 256 + threadIdx.x;
  int img = t >> 12, px = t & 4095;
  int col = px & 63;
  const float* Pi = P + ((size_t)img << 12);
  const u8* Mi = M + ((size_t)img << 12);
  float gx = 0.f, gy = 0.f;
  int cx = 0, cy = 0;
  float dc = Pi[px];
  u8 mc = Mi[px];
  if (col < 63 && mc && Mi[px + 1]) { gx = fabsf(Pi[px + 1] - dc); cx = 1; }
  if (px < 4032 && mc && Mi[px + 64]) { gy = fabsf(Pi[px + 64] - dc); cy = 1; }
  double v0 = (double)gx, v1 = (double)cx, v2 = (double)gy, v3 = (double)cy;
  for (int o = 32; o; o >>= 1) {
    v0 += __shfl_down(v0, o, 64); v1 += __shfl_down(v1, o, 64);
    v2 += __shfl_down(v2, o, 64); v3 += __shfl_down(v3, o, 64);
  }
  __shared__ double sh[4][4];
  int lane = threadIdx.x & 63, wv = threadIdx.x >> 6;
  if (lane == 0) { sh[0][wv] = v0; sh[1][wv] = v1; sh[2][wv] = v2; sh[3][wv] = v3; }
  __syncthreads();
  if (threadIdx.x == 0) {
    atomicAdd(&gI[img * 4 + 0], sh[0][0] + sh[0][1] + sh[0][2] + sh[0][3]);
    atomicAdd(&gI[img * 4 + 1], sh[1][0] + sh[1][1] + sh[1][2] + sh[1][3]);
    atomicAdd(&gI[img * 4 + 2], sh[2][0] + sh[2][1] + sh[2][2] + sh[2][3]);
    atomicAdd(&gI[img * 4 + 3], sh[3][0] + sh[3][1] + sh[3][2] + sh[3][3]);
  }
}

// ---------- finalize ----------
__global__ void k_final(const double* __restrict__ rho, const u32* __restrict__ cnt,
    const double* __restrict__ gI0, const double* __restrict__ gI1,
    const double* __restrict__ gI2, const double* __restrict__ gI3,
    float* __restrict__ out)
{
  int i = threadIdx.x;   // image
  double v[17];
  double c = cnt[i] ? (double)cnt[i] : 1.0;
  v[0] = rho[i] / c;
  for (int j = 0; j < 4; j++) {
    v[1 + 0 * 4 + j] = gI0[i * 4 + j];
    v[1 + 1 * 4 + j] = gI1[i * 4 + j];
    v[1 + 2 * 4 + j] = gI2[i * 4 + j];
    v[1 + 3 * 4 + j] = gI3[i * 4 + j];
  }
  for (int o = 32; o; o >>= 1)
    for (int k = 0; k < 17; k++) v[k] += __shfl_down(v[k], o, 64);
  if (i == 0) {
    double ssi = v[0] / (double)NIMG;
    double g = 0.0;
    for (int s = 0; s < 4; s++) {
      double gxs = v[1 + s * 4 + 0], cxs = v[1 + s * 4 + 1];
      double gys = v[1 + s * 4 + 2], cys = v[1 + s * 4 + 3];
      g += gxs / (cxs > 1.0 ? cxs : 1.0);
      g += gys / (cys > 1.0 ? cys : 1.0);
    }
    g /= 4.0;
    out[0] = (float)(ssi + 0.5 * g);
  }
}

extern "C" void kernel_launch(void* const* d_in, const int* in_sizes, int n_in,
                              void* d_out, int out_size, void* d_ws, size_t ws_size,
                              hipStream_t stream) {
  (void)in_sizes; (void)n_in; (void)out_size; (void)ws_size;
  const float4* p4 = (const float4*)d_in[0];
  const float4* y4 = (const float4*)d_in[1];
  const int4* m4 = (const int4*)d_in[2];
  const float* pf = (const float*)d_in[0];
  const float* yf = (const float*)d_in[1];
  u8* ws = (u8*)d_ws;

  u32*    Hfb  = (u32*)(ws + OFF_HFB);
  u32*    cnt  = (u32*)(ws + OFF_CNT);
  u32*    ccnt = (u32*)(ws + OFF_CCNT);
  u32*    ccnt2= (u32*)(ws + OFF_CCNT2);
  u32*    Nbl  = (u32*)(ws + OFF_NBL);
  u32*    ok   = (u32*)(ws + OFF_OK);
  u32*    selp = (u32*)(ws + OFF_SELP);
  u32*    selr = (u32*)(ws + OFF_SELR);
  u32*    nlt  = (u32*)(ws + OFF_NLT);
  double* Stot = (double*)(ws + OFF_STOT);
  double* Sbl  = (double*)(ws + OFF_SBL);
  double* Sltfb= (double*)(ws + OFF_SLTFB);
  double* rho  = (double*)(ws + OFF_RHO);
  double* gI0  = (double*)(ws + OFF_GI0);
  double* gI1  = (double*)(ws + OFF_GI1);
  double* gI2  = (double*)(ws + OFF_GI2);
  double* gI3  = (double*)(ws + OFF_GI3);
  float*  med  = (float*)(ws + OFF_MED);
  float*  sci  = (float*)(ws + OFF_SCI);
  u32*    selw = (u32*)(ws + OFF_SELW);
  float*  cand = (float*)(ws + OFF_CAND);
  u8*     mu8  = (u8*)(ws + OFF_MU8);
  float*  P1   = (float*)(ws + OFF_P1);
  u8*     M1   = (u8*)(ws + OFF_M1);
  float*  P2   = (float*)(ws + OFF_P2);
  u8*     M2   = (u8*)(ws + OFF_M2);
  float*  P3   = (float*)(ws + OFF_P3);
  u8*     M3   = (u8*)(ws + OFF_M3);

  hipMemsetAsync(d_ws, 0, SMALL_END, stream);

  k_sample<<<128, 256, 0, stream>>>(pf, yf, selw);
  k_scan0<<<NIMG * BPI, 256, 0, stream>>>(p4, y4, m4, (uchar4*)mu8, selw, cand, ccnt, cnt, Stot, Nbl, Sbl);
  k_med2<<<128, 256, 0, stream>>>(cand, ccnt, cnt, Nbl, Stot, Sbl, med, sci, ok);

  k_fb_hist<<<NIMG * BPI, 256, 0, stream>>>(p4, y4, (const uchar4*)mu8, ok, Hfb);
  k_fb_sel<<<128, 256, 0, stream>>>(Hfb, cnt, ok, selp, selr, nlt);
  k_fb_compact<<<NIMG * BPI, 256, 0, stream>>>(p4, y4, (const uchar4*)mu8, ok, selp, cand, ccnt2, Sltfb);
  k_fb_med<<<128, 256, 0, stream>>>(cand, ccnt2, cnt, ok, selp, selr, nlt, Stot, Sltfb, med, sci);

  k_fuse0<<<NIMG * NB0, 320, 0, stream>>>(pf, yf, mu8, med, sci, P1, M1, rho, gI0);
  k_gp<<<NIMG * 17, 192, 0, stream>>>(P1, M1, P2, M2, 259, 259, 129, 129, 17, gI1);
  k_gp<<<NIMG * 8, 64, 0, stream>>>(P2, M2, P3, M3, 129, 129, 64, 64, 8, gI2);
  k_grad3<<<1024, 256, 0, stream>>>(P3, M3, gI3);

  k_final<<<1, 64, 0, stream>>>(rho, cnt, gI0, gI1, gI2, gI3, (float*)d_out);
}

// Round 6
// 380.169 us; speedup vs baseline: 1.7699x; 1.0590x over previous
//
#include <hip/hip_runtime.h>
#include <stdint.h>

typedef unsigned int u32;
typedef unsigned long long u64;
typedef unsigned char u8;

#define NIMG 64
#define W0   518
#define H0   518
#define HW   268324
#define HW4  67081
#define BPI  32
#define NB0  33
#define N1 67081
#define N2 16641
#define N3 4096
#define CAP 32768
#define LCAP 1536

// ---- workspace byte offsets ----
#define OFF_HFB   0ULL           // u32[128][2048] fallback hist
#define OFF_CNT   1048576ULL     // u32[64]
#define OFF_CCNT  1048832ULL     // u32[128]
#define OFF_CCNT2 1049344ULL     // u32[128]
#define OFF_NBL   1049856ULL     // u32[128]
#define OFF_OK    1050368ULL     // u32[128]
#define OFF_SELP  1050880ULL     // u32[128]
#define OFF_SELR  1051392ULL     // u32[128]
#define OFF_NLT   1051904ULL     // u32[128]
#define OFF_STOT  1052416ULL     // double[128]
#define OFF_SBL   1053440ULL     // double[128]
#define OFF_SLTFB 1054464ULL     // double[128]
#define OFF_RHO   1055488ULL     // double[64]
#define OFF_GI0   1056000ULL     // double[64*4]
#define OFF_GI1   1058048ULL
#define OFF_GI2   1060096ULL
#define OFF_GI3   1062144ULL
#define SMALL_END 1064192ULL
#define OFF_MED   1064192ULL     // float[128]
#define OFF_SCI   1064704ULL     // float[128]
#define OFF_SELW  1065216ULL     // u32[256]
#define OFF_CAND  1067008ULL                   // float[128][CAP] = 16 MB
#define OFF_MU8   (OFF_CAND + 16777216ULL)     // u8[64*268324]
#define OFF_P1    (OFF_MU8 + 17172736ULL)
#define OFF_M1    (OFF_P1 + 17172736ULL)
#define OFF_P2    (OFF_M1 + 4293184ULL)
#define OFF_M2    (OFF_P2 + 4260096ULL)
#define OFF_P3    (OFF_M2 + 1065024ULL)
#define OFF_M3    (OFF_P3 + 1048576ULL)

__device__ __forceinline__ u32 f2key(float f) {
  u32 u = __float_as_uint(f);
  return (u & 0x80000000u) ? ~u : (u | 0x80000000u);
}
__device__ __forceinline__ float key2f(u32 k) {
  u32 u = (k & 0x80000000u) ? (k & 0x7fffffffu) : ~k;
  return __uint_as_float(u);
}

// block-wide rank-find over LDS hist h[per*256]; wave-scan based (2 barriers).
__device__ void blk_rankfind(u32* h, int per, u32 target, bool enable,
                             u32* outBin, u32* outRank)
{
  int b0 = threadIdx.x * per;
  u32 s = 0;
  for (int j = 0; j < per; j++) s += h[b0 + j];
  // intra-wave inclusive scan
  u32 x = s;
  int lane = threadIdx.x & 63;
  for (int o = 1; o < 64; o <<= 1) {
    u32 v = __shfl_up(x, o, 64);
    if (lane >= o) x += v;
  }
  __shared__ u32 wsum[4];
  int wv = threadIdx.x >> 6;
  if (lane == 63) wsum[wv] = x;
  __syncthreads();
  u32 woff = 0;
  for (int w = 0; w < wv; w++) woff += wsum[w];
  u32 cum = woff + x - s;   // exclusive prefix over threads
  for (int j = 0; j < per; j++) {
    u32 v = h[b0 + j];
    if (enable && target >= cum && target < cum + v) { *outBin = (u32)(b0 + j); *outRank = target - cum; }
    cum += v;
  }
  __syncthreads();
}

// ---------- sample: approximate median window in key space (+-128 sample ranks ~ 4 sigma) ----------
__global__ __launch_bounds__(256) void k_sample(const float* __restrict__ p,
    const float* __restrict__ y, u32* __restrict__ selw)
{
  int t = blockIdx.x, img = t >> 1;
  const float* src = ((t & 1) ? y : p) + (size_t)img * HW;
  __shared__ u32 h[2048];
  __shared__ u32 bLo, rLo, bHi, rHi;
  if (threadIdx.x == 0) { bLo = 0; rLo = 0; bHi = 2047; rHi = 0; }
  for (int i = threadIdx.x; i < 2048; i += 256) h[i] = 0;
  __syncthreads();
  for (int j = 0; j < 16; j++) {
    int s = threadIdx.x * 16 + j;
    float v = src[s * 65 + 32];
    atomicAdd(&h[f2key(v) >> 21], 1u);
  }
  __syncthreads();
  blk_rankfind(h, 8, 1919u, true, &bLo, &rLo);
  blk_rankfind(h, 8, 2175u, true, &bHi, &rHi);
  if (threadIdx.x == 0) {
    u32 k0 = bLo << 21;
    u32 k1 = (bHi >= 2047u) ? 0xFFFFFFFFu : ((bHi + 1u) << 21);
    selw[2 * t + 0] = k0;
    selw[2 * t + 1] = k1;
  }
}

// ---------- single full scan: mask write, cnt, Stot, below-window stats, window capture ----------
__global__ __launch_bounds__(256) void k_scan0(const float4* __restrict__ p,
    const float4* __restrict__ y, const int4* __restrict__ m,
    uchar4* __restrict__ mu4, const u32* __restrict__ selw,
    float* __restrict__ cand, u32* __restrict__ ccnt, u32* __restrict__ cnt,
    double* __restrict__ Stot, u32* __restrict__ Nbl, double* __restrict__ Sbl)
{
  __shared__ float capP[LCAP], capY[LCAP];
  __shared__ u32 nP, nY, baseP, baseY;
  if (threadIdx.x == 0) { nP = 0; nY = 0; }
  __syncthreads();
  int img = blockIdx.x / BPI, blk = blockIdx.x % BPI;
  u32 k0P = selw[img * 4 + 0], k1P = selw[img * 4 + 1];
  u32 k0Y = selw[img * 4 + 2], k1Y = selw[img * 4 + 3];
  const float4* pb = p + (size_t)img * HW4;
  const float4* yb = y + (size_t)img * HW4;
  const int4* mb = m + (size_t)img * HW4;
  uchar4* mo = mu4 + (size_t)img * HW4;
  int lc = 0, nB_p = 0, nB_y = 0;
  float sT_p = 0.f, sB_p = 0.f, sT_y = 0.f, sB_y = 0.f;
  for (int i = blk * 256 + threadIdx.x; i < HW4; i += BPI * 256) {
    float4 pv = pb[i], yv = yb[i];
    int4 mv = mb[i];
    uchar4 mw;
    mw.x = mv.x ? 1 : 0; mw.y = mv.y ? 1 : 0; mw.z = mv.z ? 1 : 0; mw.w = mv.w ? 1 : 0;
    mo[i] = mw;
#define SC(mm, vp, vy) if (mm) { lc++; \
      float v = vp; u32 k = f2key(v); sT_p += v; \
      if (k < k0P) { nB_p++; sB_p += v; } \
      else if (k < k1P) { u32 ix = atomicAdd(&nP, 1u); if (ix < LCAP) capP[ix] = v; } \
      v = vy; k = f2key(v); sT_y += v; \
      if (k < k0Y) { nB_y++; sB_y += v; } \
      else if (k < k1Y) { u32 ix = atomicAdd(&nY, 1u); if (ix < LCAP) capY[ix] = v; } }
    SC(mw.x, pv.x, yv.x) SC(mw.y, pv.y, yv.y) SC(mw.z, pv.z, yv.z) SC(mw.w, pv.w, yv.w)
#undef SC
  }
  __syncthreads();
  if (threadIdx.x == 0) {
    u32 np = nP, ny = nY;
    u32 addP = (np > (u32)LCAP) ? (u32)(CAP + 1) : np;
    u32 addY = (ny > (u32)LCAP) ? (u32)(CAP + 1) : ny;
    baseP = atomicAdd(&ccnt[img * 2 + 0], addP);
    baseY = atomicAdd(&ccnt[img * 2 + 1], addY);
  }
  __syncthreads();
  {
    u32 np = min(nP, (u32)LCAP), ny = min(nY, (u32)LCAP);
    float* cp = cand + (size_t)(img * 2 + 0) * CAP;
    float* cy = cand + (size_t)(img * 2 + 1) * CAP;
    for (u32 i = threadIdx.x; i < np; i += 256) { u32 g = baseP + i; if (g < CAP) cp[g] = capP[i]; }
    for (u32 i = threadIdx.x; i < ny; i += 256) { u32 g = baseY + i; if (g < CAP) cy[g] = capY[i]; }
  }
  double v0 = (double)sT_p, v1 = (double)sB_p, v2 = (double)sT_y, v3 = (double)sB_y;
  double v4 = (double)lc, v5 = (double)nB_p, v6 = (double)nB_y;
  for (int o = 32; o; o >>= 1) {
    v0 += __shfl_down(v0, o, 64); v1 += __shfl_down(v1, o, 64);
    v2 += __shfl_down(v2, o, 64); v3 += __shfl_down(v3, o, 64);
    v4 += __shfl_down(v4, o, 64); v5 += __shfl_down(v5, o, 64);
    v6 += __shfl_down(v6, o, 64);
  }
  __shared__ double sh[7][4];
  int lane = threadIdx.x & 63, wv = threadIdx.x >> 6;
  if (lane == 0) { sh[0][wv]=v0; sh[1][wv]=v1; sh[2][wv]=v2; sh[3][wv]=v3; sh[4][wv]=v4; sh[5][wv]=v5; sh[6][wv]=v6; }
  __syncthreads();
  if (threadIdx.x == 0) {
    double a[7];
    for (int k = 0; k < 7; k++) a[k] = sh[k][0] + sh[k][1] + sh[k][2] + sh[k][3];
    atomicAdd(&Stot[img * 2 + 0], a[0]);
    atomicAdd(&Sbl [img * 2 + 0], a[1]);
    atomicAdd(&Stot[img * 2 + 1], a[2]);
    atomicAdd(&Sbl [img * 2 + 1], a[3]);
    atomicAdd(&cnt[img], (u32)a[4]);
    atomicAdd(&Nbl[img * 2 + 0], (u32)a[5]);
    atomicAdd(&Nbl[img * 2 + 1], (u32)a[6]);
  }
}

// ---------- exact median + MAD among captured window: uniform key-space binning ----------
__global__ __launch_bounds__(256) void k_med2(const float* __restrict__ cand,
    const u32* __restrict__ ccnt, const u32* __restrict__ cnt,
    const u32* __restrict__ Nbl, const double* __restrict__ Stot,
    const double* __restrict__ Sbl, const u32* __restrict__ selw,
    float* __restrict__ med, float* __restrict__ sci, u32* __restrict__ ok)
{
  int t = blockIdx.x, img = t >> 1;
  u32 c = cnt[img];
  if (c == 0) {
    if (threadIdx.x == 0) { med[t] = 0.f; sci[t] = 1e8f; ok[t] = 1; }
    return;
  }
  u32 ntot = ccnt[t];
  u32 target0 = (c - 1) >> 1;
  u32 nb = Nbl[t];
  bool valid = (ntot <= (u32)CAP) && (target0 >= nb) && ((target0 - nb) < ntot);
  if (!valid) { if (threadIdx.x == 0) ok[t] = 0; return; }
  u32 n = ntot;
  const float* cd = cand + (size_t)t * CAP;
  u32 k0 = selw[2 * t + 0], k1 = selw[2 * t + 1];
  __shared__ u32 h[2048];
  __shared__ u32 sBin, sRank;
  if (threadIdx.x == 0) { sBin = 0; sRank = 0; }
  u32 curLo = k0;
  u64 curR = (u64)k1 - (u64)k0;        // >= 1
  u32 tgt = target0 - nb;              // rank among window members
  for (int pass = 0; pass < 3; pass++) {
    int s = 0;
    while (((curR - 1) >> s) >= 2048) s++;   // bins = ((curR-1)>>s)+1 <= 2048
    for (int i = threadIdx.x; i < 2048; i += 256) h[i] = 0;
    __syncthreads();
    for (u32 j = threadIdx.x; j < n; j += 256) {
      u32 k = f2key(cd[j]);
      if (k >= curLo && (u64)(k - curLo) < curR)
        atomicAdd(&h[(k - curLo) >> s], 1u);
    }
    __syncthreads();
    blk_rankfind(h, 8, tgt, true, &sBin, &sRank);
    curLo = curLo + (sBin << s);
    curR = (u64)1 << s;
    tgt = sRank;
    if (s == 0) break;                 // exact key reached
  }
  float m = key2f(curLo);
  // corrections among captured: count/sum of v < m
  u32 nlt2 = 0; float slt2 = 0.f;
  for (u32 j = threadIdx.x; j < n; j += 256) {
    float v = cd[j];
    if (v < m) { nlt2++; slt2 += v; }
  }
  double v0 = (double)nlt2, v1 = (double)slt2;
  for (int o = 32; o; o >>= 1) { v0 += __shfl_down(v0, o, 64); v1 += __shfl_down(v1, o, 64); }
  __shared__ double sh2[2][4];
  int lane = threadIdx.x & 63, wv = threadIdx.x >> 6;
  if (lane == 0) { sh2[0][wv] = v0; sh2[1][wv] = v1; }
  __syncthreads();
  if (threadIdx.x == 0) {
    double nl = (double)nb + sh2[0][0] + sh2[0][1] + sh2[0][2] + sh2[0][3];
    double sl = Sbl[t] + sh2[1][0] + sh2[1][1] + sh2[1][2] + sh2[1][3];
    double md = (double)m;
    double mad = Stot[t] + 2.0 * md * nl - 2.0 * sl - md * (double)c;
    double sc = mad / (double)c + 1e-8;
    med[t] = m; sci[t] = (float)(1.0 / sc); ok[t] = 1;
  }
}

// ---------- fallback chain (early-exit when fast path succeeded) ----------
__global__ __launch_bounds__(256) void k_fb_hist(const float4* __restrict__ p,
    const float4* __restrict__ y, const uchar4* __restrict__ mu,
    const u32* __restrict__ ok, u32* __restrict__ hist)
{
  int img = blockIdx.x / BPI, blk = blockIdx.x % BPI;
  if (ok[img * 2 + 0] && ok[img * 2 + 1]) return;
  __shared__ u32 h[4096];
  for (int i = threadIdx.x; i < 4096; i += 256) h[i] = 0;
  __syncthreads();
  const float4* pb = p + (size_t)img * HW4;
  const float4* yb = y + (size_t)img * HW4;
  const uchar4* mb = mu + (size_t)img * HW4;
  for (int i = blk * 256 + threadIdx.x; i < HW4; i += BPI * 256) {
    float4 pv = pb[i], yv = yb[i];
    uchar4 mv = mb[i];
#define FH(mm, vp, vy) if (mm) { atomicAdd(&h[f2key(vp) >> 21], 1u); atomicAdd(&h[2048u + (f2key(vy) >> 21)], 1u); }
    FH(mv.x, pv.x, yv.x) FH(mv.y, pv.y, yv.y) FH(mv.z, pv.z, yv.z) FH(mv.w, pv.w, yv.w)
#undef FH
  }
  __syncthreads();
  u32* gh = hist + (size_t)img * 4096;
  for (int b = threadIdx.x; b < 4096; b += 256) if (h[b]) atomicAdd(&gh[b], h[b]);
}

__global__ __launch_bounds__(256) void k_fb_sel(const u32* __restrict__ hist,
    const u32* __restrict__ cnt, const u32* __restrict__ ok,
    u32* __restrict__ selp, u32* __restrict__ selr, u32* __restrict__ nlt)
{
  int t = blockIdx.x, img = t >> 1;
  if (ok[t]) return;
  __shared__ u32 hh[2048];
  __shared__ u32 sBin, sRank;
  if (threadIdx.x == 0) { sBin = 0; sRank = 0; }
  const u32* gh = hist + (size_t)t * 2048;
  for (int i = threadIdx.x; i < 2048; i += 256) hh[i] = gh[i];
  __syncthreads();
  u32 c = cnt[img];
  u32 target = c ? ((c - 1) >> 1) : 0u;
  blk_rankfind(hh, 8, target, c != 0, &sBin, &sRank);
  if (threadIdx.x == 0) { selp[t] = sBin; selr[t] = sRank; nlt[t] = target - sRank; }
}

__global__ __launch_bounds__(256) void k_fb_compact(const float4* __restrict__ p,
    const float4* __restrict__ y, const uchar4* __restrict__ mu,
    const u32* __restrict__ ok, const u32* __restrict__ selp,
    float* __restrict__ cand, u32* __restrict__ ccnt2, double* __restrict__ Sltfb)
{
  int img = blockIdx.x / BPI, blk = blockIdx.x % BPI;
  if (ok[img * 2 + 0] && ok[img * 2 + 1]) return;
  u32 binP = selp[img * 2 + 0], binY = selp[img * 2 + 1];
  const float4* pb = p + (size_t)img * HW4;
  const float4* yb = y + (size_t)img * HW4;
  const uchar4* mb = mu + (size_t)img * HW4;
  float* cp = cand + (size_t)(img * 2 + 0) * CAP;
  float* cyv = cand + (size_t)(img * 2 + 1) * CAP;
  u32* ccP = &ccnt2[img * 2 + 0];
  u32* ccY = &ccnt2[img * 2 + 1];
  float sLp = 0.f, sLy = 0.f;
  for (int i = blk * 256 + threadIdx.x; i < HW4; i += BPI * 256) {
    float4 pv = pb[i], yv = yb[i];
    uchar4 mv = mb[i];
#define FC(mm, vp, vy) if (mm) { \
      float v = vp; u32 b = f2key(v) >> 21; \
      if (b < binP) sLp += v; else if (b == binP) { u32 ix = atomicAdd(ccP, 1u); if (ix < CAP) cp[ix] = v; } \
      v = vy; b = f2key(v) >> 21; \
      if (b < binY) sLy += v; else if (b == binY) { u32 ix = atomicAdd(ccY, 1u); if (ix < CAP) cyv[ix] = v; } }
    FC(mv.x, pv.x, yv.x) FC(mv.y, pv.y, yv.y) FC(mv.z, pv.z, yv.z) FC(mv.w, pv.w, yv.w)
#undef FC
  }
  double v0 = (double)sLp, v1 = (double)sLy;
  for (int o = 32; o; o >>= 1) { v0 += __shfl_down(v0, o, 64); v1 += __shfl_down(v1, o, 64); }
  __shared__ double sh[2][4];
  int lane = threadIdx.x & 63, wv = threadIdx.x >> 6;
  if (lane == 0) { sh[0][wv] = v0; sh[1][wv] = v1; }
  __syncthreads();
  if (threadIdx.x == 0) {
    atomicAdd(&Sltfb[img * 2 + 0], sh[0][0] + sh[0][1] + sh[0][2] + sh[0][3]);
    atomicAdd(&Sltfb[img * 2 + 1], sh[1][0] + sh[1][1] + sh[1][2] + sh[1][3]);
  }
}

__global__ __launch_bounds__(256) void k_fb_med(const float* __restrict__ cand,
    const u32* __restrict__ ccnt2, const u32* __restrict__ cnt,
    const u32* __restrict__ ok, const u32* __restrict__ selp,
    const u32* __restrict__ selr, const u32* __restrict__ nlt,
    const double* __restrict__ Stot, const double* __restrict__ Sltfb,
    float* __restrict__ med, float* __restrict__ sci)
{
  int t = blockIdx.x, img = t >> 1;
  if (ok[t]) return;
  u32 c = cnt[img];
  u32 n = ccnt2[t]; if (n > CAP) n = CAP;
  const float* cd = cand + (size_t)t * CAP;
  u32 target = selr[t];
  __shared__ u32 h[2048];
  __shared__ u32 sBin, sRank;
  if (threadIdx.x == 0) { sBin = 0; sRank = 0; }
  // uniform binning within the selected L0 bin (range 2^21): 2 passes exact
  u32 curLo = selp[t] << 21;
  u64 curR = (u64)1 << 21;
  u32 tgt = target;
  for (int pass = 0; pass < 2; pass++) {
    int s = 0;
    while (((curR - 1) >> s) >= 2048) s++;
    for (int i = threadIdx.x; i < 2048; i += 256) h[i] = 0;
    __syncthreads();
    for (u32 j = threadIdx.x; j < n; j += 256) {
      u32 k = f2key(cd[j]);
      if (k >= curLo && (u64)(k - curLo) < curR)
        atomicAdd(&h[(k - curLo) >> s], 1u);
    }
    __syncthreads();
    blk_rankfind(h, 8, tgt, c != 0, &sBin, &sRank);
    curLo = curLo + (sBin << s);
    curR = (u64)1 << s;
    tgt = sRank;
    if (s == 0) break;
  }
  float m = key2f(curLo);
  u32 nlt2 = 0; float slt2 = 0.f;
  for (u32 j = threadIdx.x; j < n; j += 256) {
    float v = cd[j];
    if (v < m) { nlt2++; slt2 += v; }
  }
  double v0 = (double)nlt2, v1 = (double)slt2;
  for (int o = 32; o; o >>= 1) { v0 += __shfl_down(v0, o, 64); v1 += __shfl_down(v1, o, 64); }
  __shared__ double sh2[2][4];
  int lane = threadIdx.x & 63, wv = threadIdx.x >> 6;
  if (lane == 0) { sh2[0][wv] = v0; sh2[1][wv] = v1; }
  __syncthreads();
  if (threadIdx.x == 0) {
    if (c) {
      double nl = (double)nlt[t] + sh2[0][0] + sh2[0][1] + sh2[0][2] + sh2[0][3];
      double sl = Sltfb[t] + sh2[1][0] + sh2[1][1] + sh2[1][2] + sh2[1][3];
      double md = (double)m;
      double mad = Stot[t] + 2.0 * md * nl - 2.0 * sl - md * (double)c;
      double sc = mad / (double)c + 1e-8;
      med[t] = m; sci[t] = (float)(1.0 / sc);
    } else { med[t] = 0.f; sci[t] = 1e8f; }
  }
}

// ---------- fused: D in registers + rho + scale-0 grad + pool0 ----------
__global__ __launch_bounds__(320) void k_fuse0(const float* __restrict__ p,
    const float* __restrict__ y, const u8* __restrict__ mu,
    const float* __restrict__ medv, const float* __restrict__ sciv,
    float* __restrict__ P1, u8* __restrict__ M1,
    double* __restrict__ rho, double* __restrict__ gI)
{
  int img = blockIdx.x / NB0, band = blockIdx.x % NB0;
  float mp = medv[img * 2 + 0], my = medv[img * 2 + 1];
  float ap = sciv[img * 2 + 0], ay = sciv[img * 2 + 1];
  const float* pb = p + (size_t)img * HW;
  const float* yb = y + (size_t)img * HW;
  const u8*   mb = mu + (size_t)img * HW;
  int ra = band * 16;
  int rb = min(ra + 16, H0);
  int rend = (rb < H0) ? rb + 1 : H0;
  int oc = threadIdx.x;
  bool act = oc < 259;
  int cc = act ? 2 * oc : 516;
  bool vn = act && (2 * oc + 2 < W0);
  int lane = threadIdx.x & 63;
  bool edge = (lane == 63);
  float gx = 0.f, gy = 0.f, rr = 0.f;
  int cx = 0, cy = 0;
  float pd0 = 0.f, pd1 = 0.f; u8 pm0 = 0, pm1 = 0;
  size_t rbase = (size_t)ra * W0;
  float2 pv = *(const float2*)(pb + rbase + cc);
  float2 yv = *(const float2*)(yb + rbase + cc);
  uchar2 mv = *(const uchar2*)(mb + rbase + cc);
  for (int r = ra; r < rend; ++r) {
    float2 pn2 = pv, yn2 = yv; uchar2 mn2 = mv;
    if (r + 1 < rend) {
      size_t nb2 = (size_t)(r + 1) * W0;
      pn2 = *(const float2*)(pb + nb2 + cc);
      yn2 = *(const float2*)(yb + nb2 + cc);
      mn2 = *(const uchar2*)(mb + nb2 + cc);
    }
    bool core = r < rb;
    float d0 = (pv.x - mp) * ap - (yv.x - my) * ay;
    float d1 = (pv.y - mp) * ap - (yv.y - my) * ay;
    u8 m0 = mv.x, m1 = mv.y;
    float dn = __shfl_down(d0, 1, 64);
    int mn = __shfl_down((int)m0, 1, 64);
    if (vn && edge) {
      size_t a = (size_t)r * W0 + (size_t)cc + 2;
      float pnb = pb[a], ynb = yb[a];
      dn = (pnb - mp) * ap - (ynb - my) * ay;
      mn = mb[a];
    }
    if (act) {
      float f0 = (float)m0, f1 = (float)m1;
      if (core) {
        gx += f0 * f1 * fabsf(d1 - d0); cx += (int)(m0 & m1);
        if (vn) { float fn = (float)mn; gx += f1 * fn * fabsf(dn - d1); cx += (m1 && mn) ? 1 : 0; }
        rr += f0 * fabsf(d0) + f1 * fabsf(d1);
      }
      if (r > ra) {
        gy += f0 * (float)pm0 * fabsf(d0 - pd0); cy += (int)(m0 & pm0);
        gy += f1 * (float)pm1 * fabsf(d1 - pd1); cy += (int)(m1 & pm1);
      }
      if (core && (r & 1)) {
        size_t o = (size_t)img * N1 + (size_t)(r >> 1) * 259 + oc;
        P1[o] = 0.25f * (pd0 + pd1 + d0 + d1);
        M1[o] = (u8)((pm0 | pm1 | m0 | m1) ? 1 : 0);
      }
    }
    pd0 = d0; pd1 = d1; pm0 = m0; pm1 = m1;
    pv = pn2; yv = yn2; mv = mn2;
  }
  double v0 = (double)gx, v1 = (double)cx, v2 = (double)gy, v3 = (double)cy, v4 = (double)rr;
  for (int o = 32; o; o >>= 1) {
    v0 += __shfl_down(v0, o, 64); v1 += __shfl_down(v1, o, 64);
    v2 += __shfl_down(v2, o, 64); v3 += __shfl_down(v3, o, 64);
    v4 += __shfl_down(v4, o, 64);
  }
  __shared__ double sh[5][5];
  int wv = threadIdx.x >> 6;
  if (lane == 0) { sh[0][wv] = v0; sh[1][wv] = v1; sh[2][wv] = v2; sh[3][wv] = v3; sh[4][wv] = v4; }
  __syncthreads();
  if (threadIdx.x == 0) {
    double a0 = 0, a1 = 0, a2 = 0, a3 = 0, a4 = 0;
    for (int w = 0; w < 5; w++) { a0 += sh[0][w]; a1 += sh[1][w]; a2 += sh[2][w]; a3 += sh[3][w]; a4 += sh[4][w]; }
    atomicAdd(&gI[img * 4 + 0], a0);
    atomicAdd(&gI[img * 4 + 1], a1);
    atomicAdd(&gI[img * 4 + 2], a2);
    atomicAdd(&gI[img * 4 + 3], a3);
    atomicAdd(&rho[img], a4);
  }
}

// ---------- generic grad+pool (per-image accumulators) ----------
__global__ void k_gp(const float* __restrict__ Pin,
    const u8* __restrict__ Min, float* __restrict__ Pout, u8* __restrict__ Mout,
    int Win, int Hin, int Wout, int Hout, int nb, double* __restrict__ gI)
{
  int img = blockIdx.x / nb, band = blockIdx.x % nb;
  int npixI = Win * Hin, npixO = Wout * Hout;
  const float* pb = Pin + (size_t)img * npixI;
  const u8* mb = Min + (size_t)img * npixI;
  int poolEnd = 2 * Hout;
  int ra = band * 16;
  int rb = min(ra + 16, poolEnd);
  int rbx = (band == nb - 1) ? Hin : rb;
  int rend = (rbx < Hin) ? rbx + 1 : Hin;
  float gx = 0.f, gy = 0.f;
  int cx = 0, cy = 0;
  int oc = threadIdx.x;
  if (oc < Wout) {
    int c0 = 2 * oc, c1 = c0 + 1, cn = c0 + 2;
    bool vn = cn < Win;
    bool gyn = vn && (cn >= 2 * Wout);
    float pd0 = 0.f, pd1 = 0.f, pdn = 0.f;
    u8 pm0 = 0, pm1 = 0, pmn = 0;
    for (int r = ra; r < rend; ++r) {
      bool core = r < rbx;
      int base = r * Win;
      float d0 = pb[base + c0], d1 = pb[base + c1];
      u8 m0 = mb[base + c0], m1 = mb[base + c1];
      float dn = 0.f; u8 mn = 0;
      if (vn) { dn = pb[base + cn]; mn = mb[base + cn]; }
      if (core) {
        if (m0 & m1) { gx += fabsf(d1 - d0); cx++; }
        if (vn && (m1 & mn)) { gx += fabsf(dn - d1); cx++; }
      }
      if (r > ra) {
        if (m0 & pm0) { gy += fabsf(d0 - pd0); cy++; }
        if (m1 & pm1) { gy += fabsf(d1 - pd1); cy++; }
        if (gyn && (mn & pmn)) { gy += fabsf(dn - pdn); cy++; }
      }
      if (core && (r & 1) && r < poolEnd) {
        size_t o = (size_t)img * npixO + (size_t)(r >> 1) * Wout + oc;
        Pout[o] = 0.25f * (pd0 + pd1 + d0 + d1);
        Mout[o] = (u8)((pm0 | pm1 | m0 | m1) ? 1 : 0);
      }
      pd0 = d0; pd1 = d1; pdn = dn; pm0 = m0; pm1 = m1; pmn = mn;
    }
  }
  double v0 = (double)gx, v1 = (double)cx, v2 = (double)gy, v3 = (double)cy;
  for (int o = 32; o; o >>= 1) {
    v0 += __shfl_down(v0, o, 64); v1 += __shfl_down(v1, o, 64);
    v2 += __shfl_down(v2, o, 64); v3 += __shfl_down(v3, o, 64);
  }
  __shared__ double sh[4][4];
  int lane = threadIdx.x & 63, wv = threadIdx.x >> 6;
  int nw = (blockDim.x + 63) >> 6;
  if (lane == 0) { sh[0][wv] = v0; sh[1][wv] = v1; sh[2][wv] = v2; sh[3][wv] = v3; }
  __syncthreads();
  if (threadIdx.x == 0) {
    double a0 = 0, a1 = 0, a2 = 0, a3 = 0;
    for (int w = 0; w < nw; w++) { a0 += sh[0][w]; a1 += sh[1][w]; a2 += sh[2][w]; a3 += sh[3][w]; }
    atomicAdd(&gI[img * 4 + 0], a0);
    atomicAdd(&gI[img * 4 + 1], a1);
    atomicAdd(&gI[img * 4 + 2], a2);
    atomicAdd(&gI[img * 4 + 3], a3);
  }
}

// ---------- scale-3 gradient ----------
__global__ __launch_bounds__(256) void k_grad3(const float* __restrict__ P,
    const u8* __restrict__ M, double* __restrict__ gI)
{
  int t = blockIdx.x * 256 + threadIdx.x;
  int img = t >> 12, px = t & 4095;
  int col = px & 63;
  const float* Pi = P + ((size_t)img << 12);
  const u8* Mi = M + ((size_t)img << 12);
  float gx = 0.f, gy = 0.f;
  int cx = 0, cy = 0;
  float dc = Pi[px];
  u8 mc = Mi[px];
  if (col < 63 && mc && Mi[px + 1]) { gx = fabsf(Pi[px + 1] - dc); cx = 1; }
  if (px < 4032 && mc && Mi[px + 64]) { gy = fabsf(Pi[px + 64] - dc); cy = 1; }
  double v0 = (double)gx, v1 = (double)cx, v2 = (double)gy, v3 = (double)cy;
  for (int o = 32; o; o >>= 1) {
    v0 += __shfl_down(v0, o, 64); v1 += __shfl_down(v1, o, 64);
    v2 += __shfl_down(v2, o, 64); v3 += __shfl_down(v3, o, 64);
  }
  __shared__ double sh[4][4];
  int lane = threadIdx.x & 63, wv = threadIdx.x >> 6;
  if (lane == 0) { sh[0][wv] = v0; sh[1][wv] = v1; sh[2][wv] = v2; sh[3][wv] = v3; }
  __syncthreads();
  if (threadIdx.x == 0) {
    atomicAdd(&gI[img * 4 + 0], sh[0][0] + sh[0][1] + sh[0][2] + sh[0][3]);
    atomicAdd(&gI[img * 4 + 1], sh[1][0] + sh[1][1] + sh[1][2] + sh[1][3]);
    atomicAdd(&gI[img * 4 + 2], sh[2][0] + sh[2][1] + sh[2][2] + sh[2][3]);
    atomicAdd(&gI[img * 4 + 3], sh[3][0] + sh[3][1] + sh[3][2] + sh[3][3]);
  }
}

// ---------- finalize ----------
__global__ void k_final(const double* __restrict__ rho, const u32* __restrict__ cnt,
    const double* __restrict__ gI0, const double* __restrict__ gI1,
    const double* __restrict__ gI2, const double* __restrict__ gI3,
    float* __restrict__ out)
{
  int i = threadIdx.x;   // image
  double v[17];
  double c = cnt[i] ? (double)cnt[i] : 1.0;
  v[0] = rho[i] / c;
  for (int j = 0; j < 4; j++) {
    v[1 + 0 * 4 + j] = gI0[i * 4 + j];
    v[1 + 1 * 4 + j] = gI1[i * 4 + j];
    v[1 + 2 * 4 + j] = gI2[i * 4 + j];
    v[1 + 3 * 4 + j] = gI3[i * 4 + j];
  }
  for (int o = 32; o; o >>= 1)
    for (int k = 0; k < 17; k++) v[k] += __shfl_down(v[k], o, 64);
  if (i == 0) {
    double ssi = v[0] / (double)NIMG;
    double g = 0.0;
    for (int s = 0; s < 4; s++) {
      double gxs = v[1 + s * 4 + 0], cxs = v[1 + s * 4 + 1];
      double gys = v[1 + s * 4 + 2], cys = v[1 + s * 4 + 3];
      g += gxs / (cxs > 1.0 ? cxs : 1.0);
      g += gys / (cys > 1.0 ? cys : 1.0);
    }
    g /= 4.0;
    out[0] = (float)(ssi + 0.5 * g);
  }
}

extern "C" void kernel_launch(void* const* d_in, const int* in_sizes, int n_in,
                              void* d_out, int out_size, void* d_ws, size_t ws_size,
                              hipStream_t stream) {
  (void)in_sizes; (void)n_in; (void)out_size; (void)ws_size;
  const float4* p4 = (const float4*)d_in[0];
  const float4* y4 = (const float4*)d_in[1];
  const int4* m4 = (const int4*)d_in[2];
  const float* pf = (const float*)d_in[0];
  const float* yf = (const float*)d_in[1];
  u8* ws = (u8*)d_ws;

  u32*    Hfb  = (u32*)(ws + OFF_HFB);
  u32*    cnt  = (u32*)(ws + OFF_CNT);
  u32*    ccnt = (u32*)(ws + OFF_CCNT);
  u32*    ccnt2= (u32*)(ws + OFF_CCNT2);
  u32*    Nbl  = (u32*)(ws + OFF_NBL);
  u32*    ok   = (u32*)(ws + OFF_OK);
  u32*    selp = (u32*)(ws + OFF_SELP);
  u32*    selr = (u32*)(ws + OFF_SELR);
  u32*    nlt  = (u32*)(ws + OFF_NLT);
  double* Stot = (double*)(ws + OFF_STOT);
  double* Sbl  = (double*)(ws + OFF_SBL);
  double* Sltfb= (double*)(ws + OFF_SLTFB);
  double* rho  = (double*)(ws + OFF_RHO);
  double* gI0  = (double*)(ws + OFF_GI0);
  double* gI1  = (double*)(ws + OFF_GI1);
  double* gI2  = (double*)(ws + OFF_GI2);
  double* gI3  = (double*)(ws + OFF_GI3);
  float*  med  = (float*)(ws + OFF_MED);
  float*  sci  = (float*)(ws + OFF_SCI);
  u32*    selw = (u32*)(ws + OFF_SELW);
  float*  cand = (float*)(ws + OFF_CAND);
  u8*     mu8  = (u8*)(ws + OFF_MU8);
  float*  P1   = (float*)(ws + OFF_P1);
  u8*     M1   = (u8*)(ws + OFF_M1);
  float*  P2   = (float*)(ws + OFF_P2);
  u8*     M2   = (u8*)(ws + OFF_M2);
  float*  P3   = (float*)(ws + OFF_P3);
  u8*     M3   = (u8*)(ws + OFF_M3);

  hipMemsetAsync(d_ws, 0, SMALL_END, stream);

  k_sample<<<128, 256, 0, stream>>>(pf, yf, selw);
  k_scan0<<<NIMG * BPI, 256, 0, stream>>>(p4, y4, m4, (uchar4*)mu8, selw, cand, ccnt, cnt, Stot, Nbl, Sbl);
  k_med2<<<128, 256, 0, stream>>>(cand, ccnt, cnt, Nbl, Stot, Sbl, selw, med, sci, ok);

  k_fb_hist<<<NIMG * BPI, 256, 0, stream>>>(p4, y4, (const uchar4*)mu8, ok, Hfb);
  k_fb_sel<<<128, 256, 0, stream>>>(Hfb, cnt, ok, selp, selr, nlt);
  k_fb_compact<<<NIMG * BPI, 256, 0, stream>>>(p4, y4, (const uchar4*)mu8, ok, selp, cand, ccnt2, Sltfb);
  k_fb_med<<<128, 256, 0, stream>>>(cand, ccnt2, cnt, ok, selp, selr, nlt, Stot, Sltfb, med, sci);

  k_fuse0<<<NIMG * NB0, 320, 0, stream>>>(pf, yf, mu8, med, sci, P1, M1, rho, gI0);
  k_gp<<<NIMG * 17, 192, 0, stream>>>(P1, M1, P2, M2, 259, 259, 129, 129, 17, gI1);
  k_gp<<<NIMG * 8, 64, 0, stream>>>(P2, M2, P3, M3, 129, 129, 64, 64, 8, gI2);
  k_grad3<<<1024, 256, 0, stream>>>(P3, M3, gI3);

  k_final<<<1, 64, 0, stream>>>(rho, cnt, gI0, gI1, gI2, gI3, (float*)d_out);
}

// Round 7
// 366.072 us; speedup vs baseline: 1.8380x; 1.0385x over previous
//
#include <hip/hip_runtime.h>
#include <stdint.h>

typedef unsigned int u32;
typedef unsigned long long u64;
typedef unsigned char u8;

#define NIMG 64
#define W0   518
#define H0   518
#define HW   268324
#define HW4  67081
#define BPI  32
#define NB0  33
#define N1 67081
#define N2 16641
#define CAP 32768
#define LCAP 1024

// ---- workspace layout ----
#define OFF_CNT   0ULL        // u32[64]
#define OFF_CCNT  256ULL      // u32[128]
#define OFF_NBL   768ULL      // u32[128]
#define OFF_RHO   1280ULL     // double[64]
#define OFF_STOT  1792ULL     // double[128]
#define OFF_SBL   2816ULL     // double[128]
#define OFF_GI0   3840ULL     // double[256]
#define OFF_GI1   5888ULL
#define OFF_GI2   7936ULL
#define OFF_GI3   9984ULL
#define ZERO_END  12032ULL
#define OFF_MED   12032ULL    // float[128]
#define OFF_SCI   12544ULL    // float[128]
#define OFF_SELW  13056ULL    // u32[256]
#define OFF_SWF   14080ULL    // float[256]
#define OFF_CAND  15360ULL                    // float[128][CAP]
#define OFF_MU8   (OFF_CAND + 16777216ULL)    // u8[64*HW]
#define OFF_P1    (OFF_MU8 + 17172736ULL)     // float[64*N1]
#define OFF_M1    (OFF_P1 + 17172736ULL)      // u8[64*N1]
#define OFF_P2    (OFF_M1 + 4293184ULL)       // float[64*N2]
#define OFF_M2    (OFF_P2 + 4260096ULL)       // u8[64*N2]

__device__ __forceinline__ u32 f2key(float f) {
  u32 u = __float_as_uint(f);
  return (u & 0x80000000u) ? ~u : (u | 0x80000000u);
}
__device__ __forceinline__ float key2f(u32 k) {
  u32 u = (k & 0x80000000u) ? (k & 0x7fffffffu) : ~k;
  return __uint_as_float(u);
}

// block rank-find over LDS hist h[2048] (per=8 bins/thread); wave-scan, 2 barriers.
__device__ void blk_rankfind(u32* h, u32 target, bool enable, u32* outBin, u32* outRank)
{
  int b0 = threadIdx.x * 8;
  u32 s = 0;
  for (int j = 0; j < 8; j++) s += h[b0 + j];
  u32 x = s;
  int lane = threadIdx.x & 63;
  for (int o = 1; o < 64; o <<= 1) {
    u32 v = __shfl_up(x, o, 64);
    if (lane >= o) x += v;
  }
  __shared__ u32 wsum[4];
  int wv = threadIdx.x >> 6;
  if (lane == 63) wsum[wv] = x;
  __syncthreads();
  u32 woff = 0;
  for (int w = 0; w < wv; w++) woff += wsum[w];
  u32 cum = woff + x - s;
  for (int j = 0; j < 8; j++) {
    u32 v = h[b0 + j];
    if (enable && target >= cum && target < cum + v) { *outBin = (u32)(b0 + j); *outRank = target - cum; }
    cum += v;
  }
  __syncthreads();
}

// ---------- sample window + zero the accumulator region ----------
__global__ __launch_bounds__(256) void k_sample(const float* __restrict__ p,
    const float* __restrict__ y, u32* __restrict__ selw, float* __restrict__ swf,
    u32* __restrict__ zbase)
{
  int t = blockIdx.x, img = t >> 1;
  if (t == 0) {                         // zero accumulators (3008 u32 = 12032 B)
    for (int i = threadIdx.x; i < 3008; i += 256) zbase[i] = 0;
  }
  const float* src = ((t & 1) ? y : p) + (size_t)img * HW;
  __shared__ u32 h[2048];
  __shared__ u32 bLo, rT, bHi;
  if (threadIdx.x == 0) { bLo = 0; bHi = 2047; }
  for (int i = threadIdx.x; i < 2048; i += 256) h[i] = 0;
  __syncthreads();
  for (int j = 0; j < 16; j++) {
    int s = threadIdx.x * 16 + j;
    float v = src[s * 65 + 32];
    atomicAdd(&h[f2key(v) >> 21], 1u);
  }
  __syncthreads();
  blk_rankfind(h, 1919u, true, &bLo, &rT);
  blk_rankfind(h, 2175u, true, &bHi, &rT);
  if (threadIdx.x == 0) {
    u32 k0 = bLo << 21;
    u32 k1 = (bHi >= 2047u) ? 0xFFFFFFFFu : ((bHi + 1u) << 21);
    selw[2 * t + 0] = k0;
    selw[2 * t + 1] = k1;
    float f0 = (k0 <= 0x007FFFFFu) ? __uint_as_float(0xFF800000u) : key2f(k0);
    float f1 = (k1 >= 0xFF800000u) ? __uint_as_float(0x7F800000u) : key2f(k1);
    swf[2 * t + 0] = f0;
    swf[2 * t + 1] = f1;
  }
}

// ---------- single full scan (x2 unrolled): mask write, cnt, Stot, below stats, capture ----------
__global__ __launch_bounds__(256) void k_scan0(const float4* __restrict__ p,
    const float4* __restrict__ y, const int4* __restrict__ m,
    uchar4* __restrict__ mu4, const float* __restrict__ swf,
    float* __restrict__ cand, u32* __restrict__ ccnt, u32* __restrict__ cnt,
    double* __restrict__ Stot, u32* __restrict__ Nbl, double* __restrict__ Sbl)
{
  __shared__ float capP[LCAP], capY[LCAP];
  __shared__ u32 nP, nY, baseP, baseY;
  if (threadIdx.x == 0) { nP = 0; nY = 0; }
  __syncthreads();
  int img = blockIdx.x / BPI, blk = blockIdx.x % BPI;
  float f0P = swf[img * 4 + 0], f1P = swf[img * 4 + 1];
  float f0Y = swf[img * 4 + 2], f1Y = swf[img * 4 + 3];
  const float4* pb = p + (size_t)img * HW4;
  const float4* yb = y + (size_t)img * HW4;
  const int4* mb = m + (size_t)img * HW4;
  uchar4* mo = mu4 + (size_t)img * HW4;
  int lc = 0, nBp = 0, nBy = 0;
  float sTp = 0.f, sBp = 0.f, sTy = 0.f, sBy = 0.f;

#define PEL(mm, vp, vy) if (mm) { lc++; \
      sTp += vp; \
      if (vp < f0P) { nBp++; sBp += vp; } \
      else if (vp < f1P) { u32 ix = atomicAdd(&nP, 1u); if (ix < LCAP) capP[ix] = vp; } \
      sTy += vy; \
      if (vy < f0Y) { nBy++; sBy += vy; } \
      else if (vy < f1Y) { u32 ix = atomicAdd(&nY, 1u); if (ix < LCAP) capY[ix] = vy; } }
#define PGRP(idx) { \
      float4 pv = pb[idx]; float4 yv = yb[idx]; int4 mv = mb[idx]; \
      uchar4 mw; mw.x = mv.x ? 1 : 0; mw.y = mv.y ? 1 : 0; mw.z = mv.z ? 1 : 0; mw.w = mv.w ? 1 : 0; \
      mo[idx] = mw; \
      PEL(mw.x, pv.x, yv.x) PEL(mw.y, pv.y, yv.y) PEL(mw.z, pv.z, yv.z) PEL(mw.w, pv.w, yv.w) }

  const int S = BPI * 256;
  int i = blk * 256 + threadIdx.x;
  for (; i + S < HW4; i += 2 * S) {
    float4 pa = pb[i], pc = pb[i + S];
    float4 ya = yb[i], yc = yb[i + S];
    int4 ma = mb[i], mc = mb[i + S];
    uchar4 wa, wc;
    wa.x = ma.x ? 1 : 0; wa.y = ma.y ? 1 : 0; wa.z = ma.z ? 1 : 0; wa.w = ma.w ? 1 : 0;
    wc.x = mc.x ? 1 : 0; wc.y = mc.y ? 1 : 0; wc.z = mc.z ? 1 : 0; wc.w = mc.w ? 1 : 0;
    mo[i] = wa; mo[i + S] = wc;
    PEL(wa.x, pa.x, ya.x) PEL(wa.y, pa.y, ya.y) PEL(wa.z, pa.z, ya.z) PEL(wa.w, pa.w, ya.w)
    PEL(wc.x, pc.x, yc.x) PEL(wc.y, pc.y, yc.y) PEL(wc.z, pc.z, yc.z) PEL(wc.w, pc.w, yc.w)
  }
  if (i < HW4) PGRP(i)
#undef PGRP
#undef PEL

  __syncthreads();
  if (threadIdx.x == 0) {
    u32 np = nP, ny = nY;
    u32 addP = (np > (u32)LCAP) ? (u32)(CAP + 1) : np;
    u32 addY = (ny > (u32)LCAP) ? (u32)(CAP + 1) : ny;
    baseP = atomicAdd(&ccnt[img * 2 + 0], addP);
    baseY = atomicAdd(&ccnt[img * 2 + 1], addY);
  }
  __syncthreads();
  {
    u32 np = min(nP, (u32)LCAP), ny = min(nY, (u32)LCAP);
    float* cp = cand + (size_t)(img * 2 + 0) * CAP;
    float* cy = cand + (size_t)(img * 2 + 1) * CAP;
    for (u32 k = threadIdx.x; k < np; k += 256) { u32 g = baseP + k; if (g < CAP) cp[g] = capP[k]; }
    for (u32 k = threadIdx.x; k < ny; k += 256) { u32 g = baseY + k; if (g < CAP) cy[g] = capY[k]; }
  }
  double v0 = (double)sTp, v1 = (double)sBp, v2 = (double)sTy, v3 = (double)sBy;
  double v4 = (double)lc, v5 = (double)nBp, v6 = (double)nBy;
  for (int o = 32; o; o >>= 1) {
    v0 += __shfl_down(v0, o, 64); v1 += __shfl_down(v1, o, 64);
    v2 += __shfl_down(v2, o, 64); v3 += __shfl_down(v3, o, 64);
    v4 += __shfl_down(v4, o, 64); v5 += __shfl_down(v5, o, 64);
    v6 += __shfl_down(v6, o, 64);
  }
  __shared__ double sh[7][4];
  int lane = threadIdx.x & 63, wv = threadIdx.x >> 6;
  if (lane == 0) { sh[0][wv]=v0; sh[1][wv]=v1; sh[2][wv]=v2; sh[3][wv]=v3; sh[4][wv]=v4; sh[5][wv]=v5; sh[6][wv]=v6; }
  __syncthreads();
  if (threadIdx.x == 0) {
    double a[7];
    for (int k = 0; k < 7; k++) a[k] = sh[k][0] + sh[k][1] + sh[k][2] + sh[k][3];
    atomicAdd(&Stot[img * 2 + 0], a[0]);
    atomicAdd(&Sbl [img * 2 + 0], a[1]);
    atomicAdd(&Stot[img * 2 + 1], a[2]);
    atomicAdd(&Sbl [img * 2 + 1], a[3]);
    atomicAdd(&cnt[img], (u32)a[4]);
    atomicAdd(&Nbl[img * 2 + 0], (u32)a[5]);
    atomicAdd(&Nbl[img * 2 + 1], (u32)a[6]);
  }
}

// ---------- exact median + MAD (fast path over capture; integrated exact fallback) ----------
__global__ __launch_bounds__(256) void k_med2(const float* __restrict__ cand,
    const u32* __restrict__ ccnt, const u32* __restrict__ cnt,
    const u32* __restrict__ Nbl, const double* __restrict__ Stot,
    const double* __restrict__ Sbl, const u32* __restrict__ selw,
    const float* __restrict__ pf, const float* __restrict__ yf,
    const u8* __restrict__ mu8, float* __restrict__ med, float* __restrict__ sci)
{
  int t = blockIdx.x, img = t >> 1;
  u32 c = cnt[img];
  if (c == 0) {
    if (threadIdx.x == 0) { med[t] = 0.f; sci[t] = 1e8f; }
    return;
  }
  u32 ntot = ccnt[t];
  u32 target0 = (c - 1) >> 1;
  u32 nb = Nbl[t];
  bool valid = (ntot <= (u32)CAP) && (target0 >= nb) && ((target0 - nb) < ntot);
  __shared__ u32 h[2048];
  __shared__ u32 sBin, sRank;
  if (threadIdx.x == 0) { sBin = 0; sRank = 0; }
  int lane = threadIdx.x & 63, wv = threadIdx.x >> 6;
  __shared__ double sh2[2][4];

  if (valid) {
    u32 n = ntot;
    const float* cd = cand + (size_t)t * CAP;
    u32 curLo = selw[2 * t + 0];
    u64 curR = (u64)selw[2 * t + 1] - (u64)curLo;
    u32 tgt = target0 - nb;
    for (int pass = 0; pass < 3; pass++) {
      int s = 0;
      while (((curR - 1) >> s) >= 2048) s++;
      for (int i = threadIdx.x; i < 2048; i += 256) h[i] = 0;
      __syncthreads();
      for (u32 j = threadIdx.x; j < n; j += 256) {
        u32 k = f2key(cd[j]);
        if (k >= curLo && (u64)(k - curLo) < curR)
          atomicAdd(&h[(k - curLo) >> s], 1u);
      }
      __syncthreads();
      blk_rankfind(h, tgt, true, &sBin, &sRank);
      curLo = curLo + (sBin << s);
      curR = (u64)1 << s;
      tgt = sRank;
      if (s == 0) break;
    }
    float mv = key2f(curLo);
    u32 nlt2 = 0; float slt2 = 0.f;
    for (u32 j = threadIdx.x; j < n; j += 256) {
      float v = cd[j];
      if (v < mv) { nlt2++; slt2 += v; }
    }
    double v0 = (double)nlt2, v1 = (double)slt2;
    for (int o = 32; o; o >>= 1) { v0 += __shfl_down(v0, o, 64); v1 += __shfl_down(v1, o, 64); }
    if (lane == 0) { sh2[0][wv] = v0; sh2[1][wv] = v1; }
    __syncthreads();
    if (threadIdx.x == 0) {
      double nl = (double)nb + sh2[0][0] + sh2[0][1] + sh2[0][2] + sh2[0][3];
      double sl = Sbl[t] + sh2[1][0] + sh2[1][1] + sh2[1][2] + sh2[1][3];
      double md = (double)mv;
      double mad = Stot[t] + 2.0 * md * nl - 2.0 * sl - md * (double)c;
      double sc = mad / (double)c + 1e-8;
      med[t] = mv; sci[t] = (float)(1.0 / sc);
    }
  } else {
    // exact fallback: block-local uniform-bin select over the full array (rare)
    const float* src = ((t & 1) ? yf : pf) + (size_t)img * HW;
    const u8* mk = mu8 + (size_t)img * HW;
    u32 curLo = 0; u64 curR = (u64)1 << 32; u32 tgt = target0;
    for (int pass = 0; pass < 4; pass++) {
      int s = 0;
      while (((curR - 1) >> s) >= 2048) s++;
      for (int i = threadIdx.x; i < 2048; i += 256) h[i] = 0;
      __syncthreads();
      for (u32 j = threadIdx.x; j < (u32)HW; j += 256) {
        if (mk[j]) {
          u32 k = f2key(src[j]);
          if (k >= curLo && (u64)(k - curLo) < curR)
            atomicAdd(&h[(k - curLo) >> s], 1u);
        }
      }
      __syncthreads();
      blk_rankfind(h, tgt, true, &sBin, &sRank);
      curLo = curLo + (sBin << s);
      curR = (u64)1 << s;
      tgt = sRank;
      if (s == 0) break;
    }
    float mv = key2f(curLo);
    double nl = 0.0, sl = 0.0;
    for (u32 j = threadIdx.x; j < (u32)HW; j += 256) {
      if (mk[j]) {
        float v = src[j];
        if (v < mv) { nl += 1.0; sl += (double)v; }
      }
    }
    for (int o = 32; o; o >>= 1) { nl += __shfl_down(nl, o, 64); sl += __shfl_down(sl, o, 64); }
    if (lane == 0) { sh2[0][wv] = nl; sh2[1][wv] = sl; }
    __syncthreads();
    if (threadIdx.x == 0) {
      double nlT = sh2[0][0] + sh2[0][1] + sh2[0][2] + sh2[0][3];
      double slT = sh2[1][0] + sh2[1][1] + sh2[1][2] + sh2[1][3];
      double md = (double)mv;
      double mad = Stot[t] + 2.0 * md * nlT - 2.0 * slT - md * (double)c;
      double sc = mad / (double)c + 1e-8;
      med[t] = mv; sci[t] = (float)(1.0 / sc);
    }
  }
}

// ---------- fused: D in registers + rho + scale-0 grad + pool0 (2-row pipeline) ----------
__global__ __launch_bounds__(320) void k_fuse0(const float* __restrict__ p,
    const float* __restrict__ y, const u8* __restrict__ mu,
    const float* __restrict__ medv, const float* __restrict__ sciv,
    float* __restrict__ P1, u8* __restrict__ M1,
    double* __restrict__ rho, double* __restrict__ gI)
{
  int img = blockIdx.x / NB0, band = blockIdx.x % NB0;
  float mp = medv[img * 2 + 0], my = medv[img * 2 + 1];
  float ap = sciv[img * 2 + 0], ay = sciv[img * 2 + 1];
  const float* pb = p + (size_t)img * HW;
  const float* yb = y + (size_t)img * HW;
  const u8*   mb = mu + (size_t)img * HW;
  int ra = band * 16;
  int rb = min(ra + 16, H0);
  int rend = (rb < H0) ? rb + 1 : H0;
  int oc = threadIdx.x;
  bool act = oc < 259;
  int cc = act ? 2 * oc : 516;
  bool vn = act && (2 * oc + 2 < W0);
  int lane = threadIdx.x & 63;
  bool edge = (lane == 63);
  float gx = 0.f, gy = 0.f, rr = 0.f;
  int cx = 0, cy = 0;
  float pd0 = 0.f, pd1 = 0.f; u8 pm0 = 0, pm1 = 0;
  float2 pv0, yv0, pv1, yv1;
  uchar2 mv0, mv1;
  {
    size_t a0 = (size_t)ra * W0 + cc;
    pv0 = *(const float2*)(pb + a0); yv0 = *(const float2*)(yb + a0); mv0 = *(const uchar2*)(mb + a0);
    if (ra + 1 < rend) {
      size_t a1 = a0 + W0;
      pv1 = *(const float2*)(pb + a1); yv1 = *(const float2*)(yb + a1); mv1 = *(const uchar2*)(mb + a1);
    } else { pv1 = pv0; yv1 = yv0; mv1 = mv0; }
  }
  for (int r = ra; r < rend; ++r) {
    float2 pv2 = pv1, yv2 = yv1; uchar2 mv2 = mv1;
    if (r + 2 < rend) {
      size_t a2 = (size_t)(r + 2) * W0 + cc;
      pv2 = *(const float2*)(pb + a2); yv2 = *(const float2*)(yb + a2); mv2 = *(const uchar2*)(mb + a2);
    }
    bool core = r < rb;
    float d0 = (pv0.x - mp) * ap - (yv0.x - my) * ay;
    float d1 = (pv0.y - mp) * ap - (yv0.y - my) * ay;
    u8 m0 = mv0.x, m1 = mv0.y;
    float dn = __shfl_down(d0, 1, 64);
    int mn = __shfl_down((int)m0, 1, 64);
    if (vn && edge) {
      size_t a = (size_t)r * W0 + (size_t)cc + 2;
      float pnb = pb[a], ynb = yb[a];
      dn = (pnb - mp) * ap - (ynb - my) * ay;
      mn = mb[a];
    }
    if (act) {
      float f0 = (float)m0, f1 = (float)m1;
      if (core) {
        gx += f0 * f1 * fabsf(d1 - d0); cx += (int)(m0 & m1);
        if (vn) { float fn = (float)mn; gx += f1 * fn * fabsf(dn - d1); cx += (m1 && mn) ? 1 : 0; }
        rr += f0 * fabsf(d0) + f1 * fabsf(d1);
      }
      if (r > ra) {
        gy += f0 * (float)pm0 * fabsf(d0 - pd0); cy += (int)(m0 & pm0);
        gy += f1 * (float)pm1 * fabsf(d1 - pd1); cy += (int)(m1 & pm1);
      }
      if (core && (r & 1)) {
        size_t o = (size_t)img * N1 + (size_t)(r >> 1) * 259 + oc;
        P1[o] = 0.25f * (pd0 + pd1 + d0 + d1);
        M1[o] = (u8)((pm0 | pm1 | m0 | m1) ? 1 : 0);
      }
    }
    pd0 = d0; pd1 = d1; pm0 = m0; pm1 = m1;
    pv0 = pv1; yv0 = yv1; mv0 = mv1;
    pv1 = pv2; yv1 = yv2; mv1 = mv2;
  }
  double v0 = (double)gx, v1 = (double)cx, v2 = (double)gy, v3 = (double)cy, v4 = (double)rr;
  for (int o = 32; o; o >>= 1) {
    v0 += __shfl_down(v0, o, 64); v1 += __shfl_down(v1, o, 64);
    v2 += __shfl_down(v2, o, 64); v3 += __shfl_down(v3, o, 64);
    v4 += __shfl_down(v4, o, 64);
  }
  __shared__ double sh[5][5];
  int wv = threadIdx.x >> 6;
  if (lane == 0) { sh[0][wv] = v0; sh[1][wv] = v1; sh[2][wv] = v2; sh[3][wv] = v3; sh[4][wv] = v4; }
  __syncthreads();
  if (threadIdx.x == 0) {
    double a0 = 0, a1 = 0, a2 = 0, a3 = 0, a4 = 0;
    for (int w = 0; w < 5; w++) { a0 += sh[0][w]; a1 += sh[1][w]; a2 += sh[2][w]; a3 += sh[3][w]; a4 += sh[4][w]; }
    atomicAdd(&gI[img * 4 + 0], a0);
    atomicAdd(&gI[img * 4 + 1], a1);
    atomicAdd(&gI[img * 4 + 2], a2);
    atomicAdd(&gI[img * 4 + 3], a3);
    atomicAdd(&rho[img], a4);
  }
}

// ---------- grad+pool scale 1 (259 -> 129) ----------
__global__ void k_gp(const float* __restrict__ Pin,
    const u8* __restrict__ Min, float* __restrict__ Pout, u8* __restrict__ Mout,
    int Win, int Hin, int Wout, int Hout, int nb, double* __restrict__ gI)
{
  int img = blockIdx.x / nb, band = blockIdx.x % nb;
  int npixI = Win * Hin, npixO = Wout * Hout;
  const float* pb = Pin + (size_t)img * npixI;
  const u8* mb = Min + (size_t)img * npixI;
  int poolEnd = 2 * Hout;
  int ra = band * 16;
  int rb = min(ra + 16, poolEnd);
  int rbx = (band == nb - 1) ? Hin : rb;
  int rend = (rbx < Hin) ? rbx + 1 : Hin;
  float gx = 0.f, gy = 0.f;
  int cx = 0, cy = 0;
  int oc = threadIdx.x;
  if (oc < Wout) {
    int c0 = 2 * oc, c1 = c0 + 1, cn = c0 + 2;
    bool vn = cn < Win;
    bool gyn = vn && (cn >= 2 * Wout);
    float pd0 = 0.f, pd1 = 0.f, pdn = 0.f;
    u8 pm0 = 0, pm1 = 0, pmn = 0;
    for (int r = ra; r < rend; ++r) {
      bool core = r < rbx;
      int base = r * Win;
      float d0 = pb[base + c0], d1 = pb[base + c1];
      u8 m0 = mb[base + c0], m1 = mb[base + c1];
      float dn = 0.f; u8 mn = 0;
      if (vn) { dn = pb[base + cn]; mn = mb[base + cn]; }
      if (core) {
        if (m0 & m1) { gx += fabsf(d1 - d0); cx++; }
        if (vn && (m1 & mn)) { gx += fabsf(dn - d1); cx++; }
      }
      if (r > ra) {
        if (m0 & pm0) { gy += fabsf(d0 - pd0); cy++; }
        if (m1 & pm1) { gy += fabsf(d1 - pd1); cy++; }
        if (gyn && (mn & pmn)) { gy += fabsf(dn - pdn); cy++; }
      }
      if (core && (r & 1) && r < poolEnd) {
        size_t o = (size_t)img * npixO + (size_t)(r >> 1) * Wout + oc;
        Pout[o] = 0.25f * (pd0 + pd1 + d0 + d1);
        Mout[o] = (u8)((pm0 | pm1 | m0 | m1) ? 1 : 0);
      }
      pd0 = d0; pd1 = d1; pdn = dn; pm0 = m0; pm1 = m1; pmn = mn;
    }
  }
  double v0 = (double)gx, v1 = (double)cx, v2 = (double)gy, v3 = (double)cy;
  for (int o = 32; o; o >>= 1) {
    v0 += __shfl_down(v0, o, 64); v1 += __shfl_down(v1, o, 64);
    v2 += __shfl_down(v2, o, 64); v3 += __shfl_down(v3, o, 64);
  }
  __shared__ double sh[4][4];
  int lane = threadIdx.x & 63, wv = threadIdx.x >> 6;
  int nw = (blockDim.x + 63) >> 6;
  if (lane == 0) { sh[0][wv] = v0; sh[1][wv] = v1; sh[2][wv] = v2; sh[3][wv] = v3; }
  __syncthreads();
  if (threadIdx.x == 0) {
    double a0 = 0, a1 = 0, a2 = 0, a3 = 0;
    for (int w = 0; w < nw; w++) { a0 += sh[0][w]; a1 += sh[1][w]; a2 += sh[2][w]; a3 += sh[3][w]; }
    atomicAdd(&gI[img * 4 + 0], a0);
    atomicAdd(&gI[img * 4 + 1], a1);
    atomicAdd(&gI[img * 4 + 2], a2);
    atomicAdd(&gI[img * 4 + 3], a3);
  }
}

// ---------- last level: grad2 (129x129) + in-register pool -> grad3 (64x64), no P3 write ----------
__global__ __launch_bounds__(64) void k_gp_last(const float* __restrict__ Pin,
    const u8* __restrict__ Min, double* __restrict__ gI2v, double* __restrict__ gI3v)
{
  const int Win = 129, Hin = 129, Wout = 64, nb = 8;
  int img = blockIdx.x / nb, band = blockIdx.x % nb;
  const float* pb = Pin + (size_t)img * (Win * Hin);
  const u8* mb = Min + (size_t)img * (Win * Hin);
  int ra = band * 16;
  int rb = min(ra + 16, 128);               // poolEnd = 128
  int rbx = (band == nb - 1) ? Hin : rb;
  int rend2 = (band < nb - 1) ? (ra + 18) : Hin;   // +2 halo rows for pooled halo row
  float gx = 0.f, gy = 0.f; int cx = 0, cy = 0;
  float ogx = 0.f, ogy = 0.f; int ocx = 0, ocy = 0;
  int oc = threadIdx.x;                      // 0..63, one wave
  int c0 = 2 * oc, c1 = c0 + 1, cn = c0 + 2;
  bool vn = cn < Win;
  bool gyn = vn && (cn >= 2 * Wout);         // odd last input column (oc==63)
  float pd0 = 0.f, pd1 = 0.f, pdn = 0.f;
  u8 pm0 = 0, pm1 = 0, pmn = 0;
  float ppo = 0.f; int pmo = 0; bool havePrev = false;
  for (int r = ra; r < rend2; ++r) {
    int base = r * Win;
    float d0 = pb[base + c0], d1 = pb[base + c1];
    u8 m0 = mb[base + c0], m1 = mb[base + c1];
    float dn = 0.f; u8 mn = 0;
    if (vn) { dn = pb[base + cn]; mn = mb[base + cn]; }
    if (r < rbx) {                           // input-scale x-grad rows owned
      if (m0 & m1) { gx += fabsf(d1 - d0); cx++; }
      if (vn && (m1 & mn)) { gx += fabsf(dn - d1); cx++; }
    }
    if (r > ra && r <= rb) {                 // input-scale y-grad pairs owned
      if (m0 & pm0) { gy += fabsf(d0 - pd0); cy++; }
      if (m1 & pm1) { gy += fabsf(d1 - pd1); cy++; }
      if (gyn && (mn & pmn)) { gy += fabsf(dn - pdn); cy++; }
    }
    if (r & 1) {
      bool owned = r < rb;
      bool halo = (r == rb + 1);
      if (owned || halo) {
        float po = 0.25f * (pd0 + pd1 + d0 + d1);
        int mo = (pm0 | pm1 | m0 | m1) ? 1 : 0;
        float pon = __shfl_down(po, 1, 64);
        int mon = __shfl_down(mo, 1, 64);
        if (owned && oc < 63 && mo && mon) { ogx += fabsf(pon - po); ocx++; }
        if (havePrev && mo && pmo) { ogy += fabsf(po - ppo); ocy++; }
        ppo = po; pmo = mo; havePrev = true;
      }
    }
    pd0 = d0; pd1 = d1; pdn = dn; pm0 = m0; pm1 = m1; pmn = mn;
  }
  double v[8] = {(double)gx, (double)cx, (double)gy, (double)cy,
                 (double)ogx, (double)ocx, (double)ogy, (double)ocy};
  for (int o = 32; o; o >>= 1)
    for (int k = 0; k < 8; k++) v[k] += __shfl_down(v[k], o, 64);
  if (threadIdx.x == 0) {
    atomicAdd(&gI2v[img * 4 + 0], v[0]);
    atomicAdd(&gI2v[img * 4 + 1], v[1]);
    atomicAdd(&gI2v[img * 4 + 2], v[2]);
    atomicAdd(&gI2v[img * 4 + 3], v[3]);
    atomicAdd(&gI3v[img * 4 + 0], v[4]);
    atomicAdd(&gI3v[img * 4 + 1], v[5]);
    atomicAdd(&gI3v[img * 4 + 2], v[6]);
    atomicAdd(&gI3v[img * 4 + 3], v[7]);
  }
}

// ---------- finalize ----------
__global__ void k_final(const double* __restrict__ rho, const u32* __restrict__ cnt,
    const double* __restrict__ gI0, const double* __restrict__ gI1,
    const double* __restrict__ gI2, const double* __restrict__ gI3,
    float* __restrict__ out)
{
  int i = threadIdx.x;
  double v[17];
  double c = cnt[i] ? (double)cnt[i] : 1.0;
  v[0] = rho[i] / c;
  for (int j = 0; j < 4; j++) {
    v[1 + 0 * 4 + j] = gI0[i * 4 + j];
    v[1 + 1 * 4 + j] = gI1[i * 4 + j];
    v[1 + 2 * 4 + j] = gI2[i * 4 + j];
    v[1 + 3 * 4 + j] = gI3[i * 4 + j];
  }
  for (int o = 32; o; o >>= 1)
    for (int k = 0; k < 17; k++) v[k] += __shfl_down(v[k], o, 64);
  if (i == 0) {
    double ssi = v[0] / (double)NIMG;
    double g = 0.0;
    for (int s = 0; s < 4; s++) {
      double gxs = v[1 + s * 4 + 0], cxs = v[1 + s * 4 + 1];
      double gys = v[1 + s * 4 + 2], cys = v[1 + s * 4 + 3];
      g += gxs / (cxs > 1.0 ? cxs : 1.0);
      g += gys / (cys > 1.0 ? cys : 1.0);
    }
    g /= 4.0;
    out[0] = (float)(ssi + 0.5 * g);
  }
}

extern "C" void kernel_launch(void* const* d_in, const int* in_sizes, int n_in,
                              void* d_out, int out_size, void* d_ws, size_t ws_size,
                              hipStream_t stream) {
  (void)in_sizes; (void)n_in; (void)out_size; (void)ws_size;
  const float4* p4 = (const float4*)d_in[0];
  const float4* y4 = (const float4*)d_in[1];
  const int4* m4 = (const int4*)d_in[2];
  const float* pf = (const float*)d_in[0];
  const float* yf = (const float*)d_in[1];
  u8* ws = (u8*)d_ws;

  u32*    cnt  = (u32*)(ws + OFF_CNT);
  u32*    ccnt = (u32*)(ws + OFF_CCNT);
  u32*    Nbl  = (u32*)(ws + OFF_NBL);
  double* rho  = (double*)(ws + OFF_RHO);
  double* Stot = (double*)(ws + OFF_STOT);
  double* Sbl  = (double*)(ws + OFF_SBL);
  double* gI0  = (double*)(ws + OFF_GI0);
  double* gI1  = (double*)(ws + OFF_GI1);
  double* gI2  = (double*)(ws + OFF_GI2);
  double* gI3  = (double*)(ws + OFF_GI3);
  float*  med  = (float*)(ws + OFF_MED);
  float*  sci  = (float*)(ws + OFF_SCI);
  u32*    selw = (u32*)(ws + OFF_SELW);
  float*  swf  = (float*)(ws + OFF_SWF);
  float*  cand = (float*)(ws + OFF_CAND);
  u8*     mu8  = (u8*)(ws + OFF_MU8);
  float*  P1   = (float*)(ws + OFF_P1);
  u8*     M1   = (u8*)(ws + OFF_M1);
  float*  P2   = (float*)(ws + OFF_P2);
  u8*     M2   = (u8*)(ws + OFF_M2);

  k_sample<<<128, 256, 0, stream>>>(pf, yf, selw, swf, (u32*)ws);
  k_scan0<<<NIMG * BPI, 256, 0, stream>>>(p4, y4, m4, (uchar4*)mu8, swf, cand, ccnt, cnt, Stot, Nbl, Sbl);
  k_med2<<<128, 256, 0, stream>>>(cand, ccnt, cnt, Nbl, Stot, Sbl, selw, pf, yf, mu8, med, sci);
  k_fuse0<<<NIMG * NB0, 320, 0, stream>>>(pf, yf, mu8, med, sci, P1, M1, rho, gI0);
  k_gp<<<NIMG * 17, 192, 0, stream>>>(P1, M1, P2, M2, 259, 259, 129, 129, 17, gI1);
  k_gp_last<<<NIMG * 8, 64, 0, stream>>>(P2, M2, gI2, gI3);
  k_final<<<1, 64, 0, stream>>>(rho, cnt, gI0, gI1, gI2, gI3, (float*)d_out);
}